// Round 4
// baseline (953.913 us; speedup 1.0000x reference)
//
#include <hip/hip_runtime.h>
#include <stdint.h>

#define EPSF 1e-5f
#define NEG_INF (-1e30f)

typedef float f32x4 __attribute__((ext_vector_type(4)));
typedef __bf16 bf16x8 __attribute__((ext_vector_type(8)));
typedef unsigned short u16x8 __attribute__((ext_vector_type(8)));

__device__ __forceinline__ unsigned short f2bf(float f) {
  union { float f; unsigned int u; } v; v.f = f;
  unsigned int r = v.u + 0x7FFFu + ((v.u >> 16) & 1u);
  return (unsigned short)(r >> 16);
}
__device__ __forceinline__ unsigned short f2bf_fast(float f) {
  union { float f; unsigned int u; } v; v.f = f;
  return (unsigned short)((v.u + 0x8000u) >> 16);
}

// ---------------- T0: generic 32x32 transpose
__global__ __launch_bounds__(256) void transpose_k(const float* __restrict__ src,
                                                   float* __restrict__ dst, int R, int C) {
  __shared__ float tl[32][33];
  int tx = threadIdx.x & 31, ty = threadIdx.x >> 5;
  int c0 = blockIdx.x * 32, r0 = blockIdx.y * 32;
#pragma unroll
  for (int i = 0; i < 4; i++)
    tl[ty + i * 8][tx] = src[(size_t)(r0 + ty + i * 8) * C + c0 + tx];
  __syncthreads();
#pragma unroll
  for (int i = 0; i < 4; i++)
    dst[(size_t)(c0 + ty + i * 8) * R + r0 + tx] = tl[tx][ty + i * 8];
}

// ---------------- A1: QKV projection
__global__ __launch_bounds__(256) void qkv_k(const float* __restrict__ xT,
    const float* __restrict__ Wq, const float* __restrict__ bq,
    const float* __restrict__ Wk, const float* __restrict__ bk,
    const float* __restrict__ Wv, const float* __restrict__ bv,
    float* __restrict__ Q, float* __restrict__ Kq, float* __restrict__ Vq) {
  __shared__ float xs[64 * 33];
  __shared__ float wq[32 * 33], wk[32 * 33], wvs[32 * 33];
  __shared__ float bqs[32], bks[32], bvs[32];
  int tid = threadIdx.x;
  int a = blockIdx.x;
  int tbase = blockIdx.y * 256;
#pragma unroll
  for (int i = 0; i < 4; i++) {
    int e = i * 256 + tid; int r = e >> 5, c = e & 31;
    wq[r * 33 + c] = Wq[e]; wk[r * 33 + c] = Wk[e]; wvs[r * 33 + c] = Wv[e];
  }
  if (tid < 32) { bqs[tid] = bq[tid]; bks[tid] = bk[tid]; bvs[tid] = bv[tid]; }
  int tl = tid & 63, rg = tid >> 6;
  for (int ch = 0; ch < 4; ch++) {
    __syncthreads();
#pragma unroll
    for (int i = 0; i < 8; i++) {
      int e = i * 256 + tid; int r = e >> 5, c = e & 31;
      xs[r * 33 + c] = xT[(size_t)a * 16384 + (size_t)(tbase + ch * 64) * 32 + e];
    }
    __syncthreads();
    float qa[8], ka[8], va[8];
#pragma unroll
    for (int r8 = 0; r8 < 8; r8++) {
      int r = rg * 8 + r8; qa[r8] = bqs[r]; ka[r8] = bks[r]; va[r8] = bvs[r];
    }
    for (int c = 0; c < 32; c++) {
      float xv = xs[tl * 33 + c];
#pragma unroll
      for (int r8 = 0; r8 < 8; r8++) {
        int r = rg * 8 + r8;
        qa[r8] += xv * wq[r * 33 + c];
        ka[r8] += xv * wk[r * 33 + c];
        va[r8] += xv * wvs[r * 33 + c];
      }
    }
    int t = tbase + ch * 64 + tl;
#pragma unroll
    for (int r8 = 0; r8 < 8; r8++) {
      int r = rg * 8 + r8;
      size_t o = (size_t)a * 16384 + (size_t)r * 512 + t;
      Q[o] = qa[r8]; Kq[o] = ka[r8]; Vq[o] = va[r8];
    }
  }
}

// ---------------- A2: top-U selection
__global__ __launch_bounds__(512) void topk_k(const float* __restrict__ Q,
    const float* __restrict__ Kq, const int* __restrict__ idxs,
    int* __restrict__ Mtop, int U) {
  __shared__ float Ks[2048];
  __shared__ float Ml[512];
  __shared__ float rv[8];
  __shared__ int ri[8];
  int bh = blockIdx.x;
  int tid = threadIdx.x, lane = tid & 63, wv = tid >> 6;
  size_t base = (size_t)bh * 2048;
#pragma unroll
  for (int i = 0; i < 4; i++) Ks[i * 512 + tid] = Kq[base + i * 512 + tid];
  float q0 = Q[base + tid], q1 = Q[base + 512 + tid];
  float q2 = Q[base + 1024 + tid], q3 = Q[base + 1536 + tid];
  __syncthreads();
  float mx = NEG_INF, sm = 0.f;
  for (int u = 0; u < U; u++) {
    int it = idxs[tid * U + u];
    it = min(max(it, 0), 511);
    float s = q0 * Ks[it] + q1 * Ks[512 + it] + q2 * Ks[1024 + it] + q3 * Ks[1536 + it];
    mx = fmaxf(mx, s); sm += s;
  }
  Ml[tid] = mx - sm * (1.f / 512.f);
  __syncthreads();
  for (int s_i = 0; s_i < U; s_i++) {
    float v = Ml[tid]; int ii = tid;
#pragma unroll
    for (int off = 32; off; off >>= 1) {
      float ov = __shfl_xor(v, off); int oi = __shfl_xor(ii, off);
      if (ov > v || (ov == v && oi < ii)) { v = ov; ii = oi; }
    }
    if (lane == 0) { rv[wv] = v; ri[wv] = ii; }
    __syncthreads();
    if (tid == 0) {
      float bv = rv[0]; int bi = ri[0];
      for (int w = 1; w < 8; w++)
        if (rv[w] > bv || (rv[w] == bv && ri[w] < bi)) { bv = rv[w]; bi = ri[w]; }
      Mtop[bh * U + s_i] = bi;
      Ml[bi] = NEG_INF;
    }
    __syncthreads();
  }
}

// ---------------- A3: attention core
__global__ __launch_bounds__(256) void attn_k(const float* __restrict__ Q,
    const float* __restrict__ Kq, const float* __restrict__ Vq,
    const int* __restrict__ Mtop, float* __restrict__ Ctx, int U) {
  __shared__ float Ks[2048];
  __shared__ float Vs[2048];
  __shared__ int mt[64];
  __shared__ float Qr[64][4];
  __shared__ float upd[64][4];
  int bh = blockIdx.x;
  int tid = threadIdx.x, lane = tid & 63, wv = tid >> 6;
  size_t base = (size_t)bh * 2048;
#pragma unroll
  for (int i = 0; i < 8; i++) {
    Ks[i * 256 + tid] = Kq[base + i * 256 + tid];
    Vs[i * 256 + tid] = Vq[base + i * 256 + tid];
  }
  if (tid < U) mt[tid] = Mtop[bh * U + tid];
  __syncthreads();
  if (tid < 4 * U) { int u = tid >> 2, d = tid & 3; Qr[u][d] = Q[base + d * 512 + mt[u]]; }
  __syncthreads();
  for (int u = wv; u < U; u += 4) {
    int mrow = mt[u];
    float q0 = Qr[u][0], q1 = Qr[u][1], q2 = Qr[u][2], q3 = Qr[u][3];
    float sv[8]; float lmax = NEG_INF;
#pragma unroll
    for (int jj = 0; jj < 8; jj++) {
      int k = jj * 64 + lane;
      float s = NEG_INF;
      if (k <= mrow)
        s = 0.5f * (q0 * Ks[k] + q1 * Ks[512 + k] + q2 * Ks[1024 + k] + q3 * Ks[1536 + k]);
      sv[jj] = s; lmax = fmaxf(lmax, s);
    }
#pragma unroll
    for (int off = 32; off; off >>= 1) lmax = fmaxf(lmax, __shfl_xor(lmax, off));
    float ls = 0.f, p0 = 0.f, p1 = 0.f, p2 = 0.f, p3 = 0.f;
#pragma unroll
    for (int jj = 0; jj < 8; jj++) {
      int k = jj * 64 + lane;
      if (k <= mrow) {
        float p = __expf(sv[jj] - lmax);
        ls += p; p0 += p * Vs[k]; p1 += p * Vs[512 + k];
        p2 += p * Vs[1024 + k]; p3 += p * Vs[1536 + k];
      }
    }
#pragma unroll
    for (int off = 32; off; off >>= 1) {
      ls += __shfl_xor(ls, off); p0 += __shfl_xor(p0, off); p1 += __shfl_xor(p1, off);
      p2 += __shfl_xor(p2, off); p3 += __shfl_xor(p3, off);
    }
    if (lane == 0) {
      float inv = 1.f / ls;
      upd[u][0] = p0 * inv; upd[u][1] = p1 * inv; upd[u][2] = p2 * inv; upd[u][3] = p3 * inv;
    }
  }
  __syncthreads();
  {
    float v[8];
    int b0 = wv * 512 + lane * 8;
#pragma unroll
    for (int q = 0; q < 8; q++) v[q] = Vs[b0 + q];
#pragma unroll
    for (int q = 1; q < 8; q++) v[q] += v[q - 1];
    float x = v[7];
    for (int off = 1; off < 64; off <<= 1) {
      float y = __shfl_up(x, off);
      if (lane >= off) x += y;
    }
    float excl = x - v[7];
#pragma unroll
    for (int q = 0; q < 8; q++) Vs[b0 + q] = v[q] + excl;
  }
  __syncthreads();
  if (tid < 4 * U) { int u = tid >> 2, d = tid & 3; Vs[d * 512 + mt[u]] = upd[u][d]; }
  __syncthreads();
#pragma unroll
  for (int i = 0; i < 8; i++) Ctx[base + i * 256 + tid] = Vs[i * 256 + tid];
}

// ---------------- A4: out-projection
__global__ __launch_bounds__(256) void oproj_k(const float* __restrict__ Ctx,
    const float* __restrict__ Wo, const float* __restrict__ bo, float* __restrict__ Y) {
  __shared__ float cs[32 * 256];
  __shared__ float wo[32 * 33];
  __shared__ float bos[32];
  int tid = threadIdx.x;
  int a = blockIdx.x, t0 = blockIdx.y * 256;
#pragma unroll
  for (int i = 0; i < 4; i++) {
    int e = i * 256 + tid; int r = e >> 5, c = e & 31;
    wo[r * 33 + c] = Wo[e];
  }
  if (tid < 32) bos[tid] = bo[tid];
#pragma unroll
  for (int i = 0; i < 32; i++) {
    int e = i * 256 + tid; int row = e >> 8, col = e & 255;
    cs[e] = Ctx[(size_t)a * 16384 + (size_t)row * 512 + t0 + col];
  }
  __syncthreads();
  int rl = tid & 31, tw = tid >> 5;
  for (int ti = 0; ti < 32; ti++) {
    int t = ti * 8 + tw;
    float acc = bos[rl];
#pragma unroll
    for (int rp = 0; rp < 32; rp++) acc += cs[rp * 256 + t] * wo[rl * 33 + rp];
    Y[(size_t)a * 16384 + (size_t)(t0 + t) * 32 + rl] = acc;
  }
}

// ---------------- T1: transpose + relu + res1 + bn1 -> Xh fp32 + f bf16
__global__ __launch_bounds__(256) void bn1t_k(const float* __restrict__ Y,
    const float* __restrict__ x, const float* __restrict__ g1, const float* __restrict__ be1,
    const float* __restrict__ me1, const float* __restrict__ va1,
    float* __restrict__ Xh, unsigned short* __restrict__ Fb) {
  __shared__ float tl[32][33];
  int tx = threadIdx.x & 31, ty = threadIdx.x >> 5;
  int c0 = blockIdx.x * 32;
  int r0 = blockIdx.y * 32;
#pragma unroll
  for (int i = 0; i < 4; i++)
    tl[ty + i * 8][tx] = Y[(size_t)(r0 + ty + i * 8) * 16384 + c0 + tx];
  __syncthreads();
#pragma unroll
  for (int i = 0; i < 4; i++) {
    int m = c0 + ty + i * 8;
    int a = r0 + tx;
    float v = tl[tx][ty + i * 8];
    int ch = m & 31;
    size_t oi = (size_t)m * 128 + a;
    float val = fmaxf(v, 0.f) + x[oi];
    float s = g1[ch] * rsqrtf(va1[ch] + EPSF);
    float res = (val - me1[ch]) * s + be1[ch];
    Xh[oi] = res;
    Fb[oi] = f2bf(res);
  }
}

// ---------------- Direct-load GEMM: C[m][n] = sum_k A[m][k] * Bw[n][k]
// No LDS, no barriers. Both operands' MFMA fragments (row = lane&15,
// k = (lane>>4)*8) are loaded straight from global with full-128B-line
// dwordx4s; B fp32 converted to bf16 in registers. Register double-buffer
// (prefetch k+2/k+3 while computing k/k+1). Reuse via L1 (wave pairs) and
// L2 (A resident per XCD; B streamed once per XCD via sibling swizzle).
// EPI 0: relu(acc+bias) -> bf16 Hout.  EPI 1: bn2(relu(acc+bias)+res2) -> fp32 Out.
template <int MI, int NJ, int EPI>
__global__ __launch_bounds__(256, 2) void gemm_direct(
    const unsigned short* __restrict__ A, const float* __restrict__ Bw,
    const float* __restrict__ bias, int K, int N, int MT, int nPerXcd,
    unsigned short* __restrict__ Hout, const float* __restrict__ res2,
    const float* __restrict__ g2, const float* __restrict__ be2,
    const float* __restrict__ me2, const float* __restrict__ va2,
    float* __restrict__ Out) {
  constexpr int BM = MI * 32;   // 2 waves in m
  constexpr int BN = NJ * 32;   // 2 waves in n
  int tid = threadIdx.x;
  int lane = tid & 63, wv = tid >> 6;
  int wm = wv >> 1, wn = wv & 1;
  // XCD swizzle: MT m-siblings sharing a W strip land on the same XCD.
  int lin = blockIdx.x;
  int xcd = lin & 7, slot = lin >> 3;
  int mt = slot % MT, nt = xcd * nPerXcd + slot / MT;
  int m0 = mt * BM + wm * (BM / 2);
  int n0 = nt * BN + wn * (BN / 2);
  int frow = lane & 15, q = lane >> 4;

  const unsigned short* ap[MI];
  const float* bp[NJ];
#pragma unroll
  for (int i = 0; i < MI; i++) ap[i] = A + (size_t)(m0 + i * 16 + frow) * K + q * 8;
#pragma unroll
  for (int j = 0; j < NJ; j++) bp[j] = Bw + (size_t)(n0 + j * 16 + frow) * K + q * 8;

  f32x4 acc[MI][NJ];
#pragma unroll
  for (int i = 0; i < MI; i++)
#pragma unroll
    for (int j = 0; j < NJ; j++) { f32x4 z = {0.f, 0.f, 0.f, 0.f}; acc[i][j] = z; }

  u16x8 a0[MI], a1[MI];
  float4 b0[NJ][2], b1[NJ][2];

  auto load = [&](u16x8 (&av)[MI], float4 (&bv)[NJ][2], int k0) {
#pragma unroll
    for (int i = 0; i < MI; i++) av[i] = *(const u16x8*)(ap[i] + k0);
#pragma unroll
    for (int j = 0; j < NJ; j++) {
      bv[j][0] = *(const float4*)(bp[j] + k0);
      bv[j][1] = *(const float4*)(bp[j] + k0 + 4);
    }
  };
  auto step = [&](u16x8 (&av)[MI], float4 (&bv)[NJ][2]) {
    bf16x8 bf[NJ];
#pragma unroll
    for (int j = 0; j < NJ; j++) {
      union { u16x8 u; bf16x8 b; } cv;
      cv.u[0] = f2bf_fast(bv[j][0].x); cv.u[1] = f2bf_fast(bv[j][0].y);
      cv.u[2] = f2bf_fast(bv[j][0].z); cv.u[3] = f2bf_fast(bv[j][0].w);
      cv.u[4] = f2bf_fast(bv[j][1].x); cv.u[5] = f2bf_fast(bv[j][1].y);
      cv.u[6] = f2bf_fast(bv[j][1].z); cv.u[7] = f2bf_fast(bv[j][1].w);
      bf[j] = cv.b;
    }
#pragma unroll
    for (int i = 0; i < MI; i++) {
      union { u16x8 u; bf16x8 b; } ca; ca.u = av[i];
#pragma unroll
      for (int j = 0; j < NJ; j++)
        acc[i][j] = __builtin_amdgcn_mfma_f32_16x16x32_bf16(ca.b, bf[j], acc[i][j], 0, 0, 0);
    }
  };

  int nk = K >> 5;  // K multiple of 64 assumed (128 / 256 iters here)
  load(a0, b0, 0);
  load(a1, b1, 32);
  for (int k = 0; k < nk; k += 2) {
    step(a0, b0);
    if (k + 2 < nk) load(a0, b0, (k + 2) * 32);
    step(a1, b1);
    if (k + 3 < nk) load(a1, b1, (k + 3) * 32);
  }

#pragma unroll
  for (int i = 0; i < MI; i++)
#pragma unroll
    for (int j = 0; j < NJ; j++) {
      int n = n0 + j * 16 + frow;
      int mb = m0 + i * 16 + (q << 2);
      float bb = bias[n];
      if constexpr (EPI == 0) {
#pragma unroll
        for (int r = 0; r < 4; r++) {
          float v = fmaxf(acc[i][j][r] + bb, 0.f);
          Hout[(size_t)(mb + r) * N + n] = f2bf(v);
        }
      } else {
        int ch = n >> 7;
        float s = g2[ch] * rsqrtf(va2[ch] + EPSF);
        float mu = me2[ch], bt = be2[ch];
#pragma unroll
        for (int r = 0; r < 4; r++) {
          float v = fmaxf(acc[i][j][r] + bb, 0.f);
          size_t oi = (size_t)(mb + r) * N + n;
          v += res2[oi];
          Out[oi] = (v - mu) * s + bt;
        }
      }
    }
}

extern "C" void kernel_launch(void* const* d_in, const int* in_sizes, int n_in,
                              void* d_out, int out_size, void* d_ws, size_t ws_size,
                              hipStream_t stream) {
  const float* x  = (const float*)d_in[0];
  const float* Wq = (const float*)d_in[1];  const float* bq = (const float*)d_in[2];
  const float* Wk = (const float*)d_in[3];  const float* bk = (const float*)d_in[4];
  const float* Wv = (const float*)d_in[5];  const float* bv = (const float*)d_in[6];
  const float* Wo = (const float*)d_in[7];  const float* bo = (const float*)d_in[8];
  const float* g1 = (const float*)d_in[9];  const float* be1 = (const float*)d_in[10];
  const float* me1 = (const float*)d_in[11]; const float* va1 = (const float*)d_in[12];
  const float* W1 = (const float*)d_in[13]; const float* b1 = (const float*)d_in[14];
  const float* W2 = (const float*)d_in[15]; const float* b2 = (const float*)d_in[16];
  const float* g2 = (const float*)d_in[17]; const float* be2 = (const float*)d_in[18];
  const float* me2 = (const float*)d_in[19]; const float* va2 = (const float*)d_in[20];
  const int* idxs = (const int*)d_in[21];
  int U = in_sizes[21] / 512;
  float* out = (float*)d_out;

  char* ws = (char*)d_ws;
  float* QC = (float*)(ws);                    // 8 MB: Q, then Ctx
  float* Kb = (float*)(ws + (8u << 20));       // 8 MB: K, then h bf16
  float* Vb = (float*)(ws + (16u << 20));      // 8 MB: V, then f bf16
  float* YT = (float*)(ws + (24u << 20));      // 8 MB: xT, then Y
  float* Xh = (float*)(ws + (32u << 20));      // 8 MB: res2 fp32
  int* Mtop = (int*)(ws + (40u << 20));
  unsigned short* Fb = (unsigned short*)Vb;
  unsigned short* Hb = (unsigned short*)Kb;

  dim3 b256(256);
  transpose_k<<<dim3(4, 512), b256, 0, stream>>>(x, YT, 16384, 128);
  qkv_k<<<dim3(128, 2), b256, 0, stream>>>(YT, Wq, bq, Wk, bk, Wv, bv, QC, Kb, Vb);
  topk_k<<<dim3(1024), dim3(512), 0, stream>>>(QC, Kb, idxs, Mtop, U);
  attn_k<<<dim3(1024), b256, 0, stream>>>(QC, Kb, Vb, Mtop, QC, U);
  oproj_k<<<dim3(128, 2), b256, 0, stream>>>(QC, Wo, bo, YT);
  bn1t_k<<<dim3(512, 4), b256, 0, stream>>>(YT, x, g1, be1, me1, va1, Xh, Fb);
  // G1: h = relu(f @ W1^T + b1) -> bf16 [512][8192]
  //     tiles 128x64 (MI=4,NJ=2), grid = 4 * 128 = 512, MT=4, nPerXcd = 128/8
  gemm_direct<4, 2, 0><<<dim3(512), b256, 0, stream>>>(
      Fb, W1, b1, 4096, 8192, 4, 16, Hb, nullptr, nullptr, nullptr, nullptr, nullptr, nullptr);
  // G2: out = bn2(relu(h @ W2^T + b2) + Xh) -> fp32 [512][4096]
  //     tiles 64x64 (MI=2,NJ=2), grid = 8 * 64 = 512, MT=8, nPerXcd = 64/8
  gemm_direct<2, 2, 1><<<dim3(512), b256, 0, stream>>>(
      Hb, W2, b2, 8192, 4096, 8, 8, nullptr, Xh, g2, be2, me2, va2, out);
}

// Round 5
// 630.318 us; speedup vs baseline: 1.5134x; 1.5134x over previous
//
#include <hip/hip_runtime.h>
#include <stdint.h>

#define EPSF 1e-5f
#define NEG_INF (-1e30f)

typedef float f32x4 __attribute__((ext_vector_type(4)));
typedef __bf16 bf16x8 __attribute__((ext_vector_type(8)));
typedef unsigned short u16x8 __attribute__((ext_vector_type(8)));

typedef __attribute__((address_space(3))) unsigned char* as3_ptr;
typedef const __attribute__((address_space(1))) unsigned char* as1_ptr;

__device__ __forceinline__ void async16(const void* g, void* l) {
  __builtin_amdgcn_global_load_lds((as1_ptr)g, (as3_ptr)l, 16, 0, 0);
}

__device__ __forceinline__ unsigned short f2bf(float f) {
  union { float f; unsigned int u; } v; v.f = f;
  unsigned int r = v.u + 0x7FFFu + ((v.u >> 16) & 1u);
  return (unsigned short)(r >> 16);
}
__device__ __forceinline__ unsigned short f2bf_fast(float f) {
  union { float f; unsigned int u; } v; v.f = f;
  return (unsigned short)((v.u + 0x8000u) >> 16);
}

// ---------------- T0: generic 32x32 transpose
__global__ __launch_bounds__(256) void transpose_k(const float* __restrict__ src,
                                                   float* __restrict__ dst, int R, int C) {
  __shared__ float tl[32][33];
  int tx = threadIdx.x & 31, ty = threadIdx.x >> 5;
  int c0 = blockIdx.x * 32, r0 = blockIdx.y * 32;
#pragma unroll
  for (int i = 0; i < 4; i++)
    tl[ty + i * 8][tx] = src[(size_t)(r0 + ty + i * 8) * C + c0 + tx];
  __syncthreads();
#pragma unroll
  for (int i = 0; i < 4; i++)
    dst[(size_t)(c0 + ty + i * 8) * R + r0 + tx] = tl[tx][ty + i * 8];
}

// ---------------- A1: QKV projection
__global__ __launch_bounds__(256) void qkv_k(const float* __restrict__ xT,
    const float* __restrict__ Wq, const float* __restrict__ bq,
    const float* __restrict__ Wk, const float* __restrict__ bk,
    const float* __restrict__ Wv, const float* __restrict__ bv,
    float* __restrict__ Q, float* __restrict__ Kq, float* __restrict__ Vq) {
  __shared__ float xs[64 * 33];
  __shared__ float wq[32 * 33], wk[32 * 33], wvs[32 * 33];
  __shared__ float bqs[32], bks[32], bvs[32];
  int tid = threadIdx.x;
  int a = blockIdx.x;
  int tbase = blockIdx.y * 256;
#pragma unroll
  for (int i = 0; i < 4; i++) {
    int e = i * 256 + tid; int r = e >> 5, c = e & 31;
    wq[r * 33 + c] = Wq[e]; wk[r * 33 + c] = Wk[e]; wvs[r * 33 + c] = Wv[e];
  }
  if (tid < 32) { bqs[tid] = bq[tid]; bks[tid] = bk[tid]; bvs[tid] = bv[tid]; }
  int tl = tid & 63, rg = tid >> 6;
  for (int ch = 0; ch < 4; ch++) {
    __syncthreads();
#pragma unroll
    for (int i = 0; i < 8; i++) {
      int e = i * 256 + tid; int r = e >> 5, c = e & 31;
      xs[r * 33 + c] = xT[(size_t)a * 16384 + (size_t)(tbase + ch * 64) * 32 + e];
    }
    __syncthreads();
    float qa[8], ka[8], va[8];
#pragma unroll
    for (int r8 = 0; r8 < 8; r8++) {
      int r = rg * 8 + r8; qa[r8] = bqs[r]; ka[r8] = bks[r]; va[r8] = bvs[r];
    }
    for (int c = 0; c < 32; c++) {
      float xv = xs[tl * 33 + c];
#pragma unroll
      for (int r8 = 0; r8 < 8; r8++) {
        int r = rg * 8 + r8;
        qa[r8] += xv * wq[r * 33 + c];
        ka[r8] += xv * wk[r * 33 + c];
        va[r8] += xv * wvs[r * 33 + c];
      }
    }
    int t = tbase + ch * 64 + tl;
#pragma unroll
    for (int r8 = 0; r8 < 8; r8++) {
      int r = rg * 8 + r8;
      size_t o = (size_t)a * 16384 + (size_t)r * 512 + t;
      Q[o] = qa[r8]; Kq[o] = ka[r8]; Vq[o] = va[r8];
    }
  }
}

// ---------------- A2: top-U selection
__global__ __launch_bounds__(512) void topk_k(const float* __restrict__ Q,
    const float* __restrict__ Kq, const int* __restrict__ idxs,
    int* __restrict__ Mtop, int U) {
  __shared__ float Ks[2048];
  __shared__ float Ml[512];
  __shared__ float rv[8];
  __shared__ int ri[8];
  int bh = blockIdx.x;
  int tid = threadIdx.x, lane = tid & 63, wv = tid >> 6;
  size_t base = (size_t)bh * 2048;
#pragma unroll
  for (int i = 0; i < 4; i++) Ks[i * 512 + tid] = Kq[base + i * 512 + tid];
  float q0 = Q[base + tid], q1 = Q[base + 512 + tid];
  float q2 = Q[base + 1024 + tid], q3 = Q[base + 1536 + tid];
  __syncthreads();
  float mx = NEG_INF, sm = 0.f;
  for (int u = 0; u < U; u++) {
    int it = idxs[tid * U + u];
    it = min(max(it, 0), 511);
    float s = q0 * Ks[it] + q1 * Ks[512 + it] + q2 * Ks[1024 + it] + q3 * Ks[1536 + it];
    mx = fmaxf(mx, s); sm += s;
  }
  Ml[tid] = mx - sm * (1.f / 512.f);
  __syncthreads();
  for (int s_i = 0; s_i < U; s_i++) {
    float v = Ml[tid]; int ii = tid;
#pragma unroll
    for (int off = 32; off; off >>= 1) {
      float ov = __shfl_xor(v, off); int oi = __shfl_xor(ii, off);
      if (ov > v || (ov == v && oi < ii)) { v = ov; ii = oi; }
    }
    if (lane == 0) { rv[wv] = v; ri[wv] = ii; }
    __syncthreads();
    if (tid == 0) {
      float bv = rv[0]; int bi = ri[0];
      for (int w = 1; w < 8; w++)
        if (rv[w] > bv || (rv[w] == bv && ri[w] < bi)) { bv = rv[w]; bi = ri[w]; }
      Mtop[bh * U + s_i] = bi;
      Ml[bi] = NEG_INF;
    }
    __syncthreads();
  }
}

// ---------------- A3: attention core
__global__ __launch_bounds__(256) void attn_k(const float* __restrict__ Q,
    const float* __restrict__ Kq, const float* __restrict__ Vq,
    const int* __restrict__ Mtop, float* __restrict__ Ctx, int U) {
  __shared__ float Ks[2048];
  __shared__ float Vs[2048];
  __shared__ int mt[64];
  __shared__ float Qr[64][4];
  __shared__ float upd[64][4];
  int bh = blockIdx.x;
  int tid = threadIdx.x, lane = tid & 63, wv = tid >> 6;
  size_t base = (size_t)bh * 2048;
#pragma unroll
  for (int i = 0; i < 8; i++) {
    Ks[i * 256 + tid] = Kq[base + i * 256 + tid];
    Vs[i * 256 + tid] = Vq[base + i * 256 + tid];
  }
  if (tid < U) mt[tid] = Mtop[bh * U + tid];
  __syncthreads();
  if (tid < 4 * U) { int u = tid >> 2, d = tid & 3; Qr[u][d] = Q[base + d * 512 + mt[u]]; }
  __syncthreads();
  for (int u = wv; u < U; u += 4) {
    int mrow = mt[u];
    float q0 = Qr[u][0], q1 = Qr[u][1], q2 = Qr[u][2], q3 = Qr[u][3];
    float sv[8]; float lmax = NEG_INF;
#pragma unroll
    for (int jj = 0; jj < 8; jj++) {
      int k = jj * 64 + lane;
      float s = NEG_INF;
      if (k <= mrow)
        s = 0.5f * (q0 * Ks[k] + q1 * Ks[512 + k] + q2 * Ks[1024 + k] + q3 * Ks[1536 + k]);
      sv[jj] = s; lmax = fmaxf(lmax, s);
    }
#pragma unroll
    for (int off = 32; off; off >>= 1) lmax = fmaxf(lmax, __shfl_xor(lmax, off));
    float ls = 0.f, p0 = 0.f, p1 = 0.f, p2 = 0.f, p3 = 0.f;
#pragma unroll
    for (int jj = 0; jj < 8; jj++) {
      int k = jj * 64 + lane;
      if (k <= mrow) {
        float p = __expf(sv[jj] - lmax);
        ls += p; p0 += p * Vs[k]; p1 += p * Vs[512 + k];
        p2 += p * Vs[1024 + k]; p3 += p * Vs[1536 + k];
      }
    }
#pragma unroll
    for (int off = 32; off; off >>= 1) {
      ls += __shfl_xor(ls, off); p0 += __shfl_xor(p0, off); p1 += __shfl_xor(p1, off);
      p2 += __shfl_xor(p2, off); p3 += __shfl_xor(p3, off);
    }
    if (lane == 0) {
      float inv = 1.f / ls;
      upd[u][0] = p0 * inv; upd[u][1] = p1 * inv; upd[u][2] = p2 * inv; upd[u][3] = p3 * inv;
    }
  }
  __syncthreads();
  {
    float v[8];
    int b0 = wv * 512 + lane * 8;
#pragma unroll
    for (int q = 0; q < 8; q++) v[q] = Vs[b0 + q];
#pragma unroll
    for (int q = 1; q < 8; q++) v[q] += v[q - 1];
    float x = v[7];
    for (int off = 1; off < 64; off <<= 1) {
      float y = __shfl_up(x, off);
      if (lane >= off) x += y;
    }
    float excl = x - v[7];
#pragma unroll
    for (int q = 0; q < 8; q++) Vs[b0 + q] = v[q] + excl;
  }
  __syncthreads();
  if (tid < 4 * U) { int u = tid >> 2, d = tid & 3; Vs[d * 512 + mt[u]] = upd[u][d]; }
  __syncthreads();
#pragma unroll
  for (int i = 0; i < 8; i++) Ctx[base + i * 256 + tid] = Vs[i * 256 + tid];
}

// ---------------- A4: out-projection
__global__ __launch_bounds__(256) void oproj_k(const float* __restrict__ Ctx,
    const float* __restrict__ Wo, const float* __restrict__ bo, float* __restrict__ Y) {
  __shared__ float cs[32 * 256];
  __shared__ float wo[32 * 33];
  __shared__ float bos[32];
  int tid = threadIdx.x;
  int a = blockIdx.x, t0 = blockIdx.y * 256;
#pragma unroll
  for (int i = 0; i < 4; i++) {
    int e = i * 256 + tid; int r = e >> 5, c = e & 31;
    wo[r * 33 + c] = Wo[e];
  }
  if (tid < 32) bos[tid] = bo[tid];
#pragma unroll
  for (int i = 0; i < 32; i++) {
    int e = i * 256 + tid; int row = e >> 8, col = e & 255;
    cs[e] = Ctx[(size_t)a * 16384 + (size_t)row * 512 + t0 + col];
  }
  __syncthreads();
  int rl = tid & 31, tw = tid >> 5;
  for (int ti = 0; ti < 32; ti++) {
    int t = ti * 8 + tw;
    float acc = bos[rl];
#pragma unroll
    for (int rp = 0; rp < 32; rp++) acc += cs[rp * 256 + t] * wo[rl * 33 + rp];
    Y[(size_t)a * 16384 + (size_t)(t0 + t) * 32 + rl] = acc;
  }
}

// ---------------- T1: transpose + relu + res1 + bn1 -> Xh fp32 + f bf16
__global__ __launch_bounds__(256) void bn1t_k(const float* __restrict__ Y,
    const float* __restrict__ x, const float* __restrict__ g1, const float* __restrict__ be1,
    const float* __restrict__ me1, const float* __restrict__ va1,
    float* __restrict__ Xh, unsigned short* __restrict__ Fb) {
  __shared__ float tl[32][33];
  int tx = threadIdx.x & 31, ty = threadIdx.x >> 5;
  int c0 = blockIdx.x * 32;
  int r0 = blockIdx.y * 32;
#pragma unroll
  for (int i = 0; i < 4; i++)
    tl[ty + i * 8][tx] = Y[(size_t)(r0 + ty + i * 8) * 16384 + c0 + tx];
  __syncthreads();
#pragma unroll
  for (int i = 0; i < 4; i++) {
    int m = c0 + ty + i * 8;
    int a = r0 + tx;
    float v = tl[tx][ty + i * 8];
    int ch = m & 31;
    size_t oi = (size_t)m * 128 + a;
    float val = fmaxf(v, 0.f) + x[oi];
    float s = g1[ch] * rsqrtf(va1[ch] + EPSF);
    float res = (val - me1[ch]) * s + be1[ch];
    Xh[oi] = res;
    Fb[oi] = f2bf(res);
  }
}

// ---------------- m97-style GEMM, split-K capable.
// C[m][n] = sum_k A[m][k]*Bw[n][k]; A bf16 [M][K], Bw fp32 [N][K].
// Single 16KB LDS buffer, 2-barrier K-loop, 4 blocks/CU via split-K grid.
// EPI 0: relu(acc+bias)->bf16 Hout.  EPI 1: bn2(relu(acc+bias)+res2)->fp32 Out.
// EPI 2: raw fp32 partial at Pout + sp*M*N.
template <int MI, int NJ, int EPI>
__global__ __launch_bounds__(256) void gemm_ps(
    const unsigned short* __restrict__ A, const float* __restrict__ Bw,
    const float* __restrict__ bias, int K, int N, int MT, int NPX, int SPLITK,
    float* __restrict__ Pout, int M,
    unsigned short* __restrict__ Hout, const float* __restrict__ res2,
    const float* __restrict__ g2, const float* __restrict__ be2,
    const float* __restrict__ me2, const float* __restrict__ va2,
    float* __restrict__ Out) {
  constexpr int BM = MI * 32;                 // 128
  constexpr int BN = NJ * 32;                 // 64
  constexpr int ABYTES = BM * 32 * 2;         // 8KB
  constexpr int BBYTES = BN * 32 * 4;         // 8KB
  constexpr int SA = ABYTES / 4096;           // 2
  constexpr int SB = BBYTES / 4096;           // 2
  __shared__ unsigned char lds[ABYTES + BBYTES];  // 16KB

  int tid = threadIdx.x;
  int lane = tid & 63, wv = tid >> 6;
  int wm = wv >> 1, wn = wv & 1;
  int lin = blockIdx.x;
  int xcd = lin & 7, slot = lin >> 3;
  int tilesPerSp = MT * NPX;
  int sp = slot / tilesPerSp;
  int rem = slot % tilesPerSp;
  int mt = rem % MT;
  int nt = xcd * NPX + rem / MT;
  int m0 = mt * BM + wm * (BM / 2);
  int n0 = nt * BN + wn * (BN / 2);
  int frow = lane & 15, q = lane >> 4;

  int nk = K / (32 * SPLITK);
  int kbase = sp * (K / SPLITK);

  f32x4 acc[MI][NJ];
#pragma unroll
  for (int i = 0; i < MI; i++)
#pragma unroll
    for (int j = 0; j < NJ; j++) { f32x4 z = {0.f, 0.f, 0.f, 0.f}; acc[i][j] = z; }

  int mtile0 = mt * BM;   // block-level A tile origin (staging covers all BM rows)
  int ntile0 = nt * BN;

  for (int k = 0; k < nk; k++) {
    int ks = kbase + k * 32;
#pragma unroll
    for (int i = 0; i < SA; i++) {
      int e = i * 256 + tid;
      int row = e >> 2;
      int g = (e & 3) ^ ((row >> 1) & 3);
      async16(A + (size_t)(mtile0 + row) * K + ks + g * 8, lds + i * 4096 + wv * 1024);
    }
#pragma unroll
    for (int i = 0; i < SB; i++) {
      int e = i * 256 + tid;
      int row = e >> 3;
      int g = (e & 7) ^ (row & 7);
      async16(Bw + (size_t)(ntile0 + row) * K + ks + g * 4,
              lds + ABYTES + i * 4096 + wv * 1024);
    }
    __syncthreads();  // drains vmcnt before barrier
    bf16x8 af[MI];
    bf16x8 bfr[NJ];
#pragma unroll
    for (int i = 0; i < MI; i++) {
      int row = wm * (BM / 2) + i * 16 + frow;
      af[i] = *(const bf16x8*)(lds + row * 64 + ((q ^ ((row >> 1) & 3)) << 4));
    }
#pragma unroll
    for (int j = 0; j < NJ; j++) {
      int row = wn * (BN / 2) + j * 16 + frow;
      const unsigned char* rb = lds + ABYTES + row * 128;
      int sw = row & 7;
      float4 w0 = *(const float4*)(rb + (((2 * q + 0) ^ sw) << 4));
      float4 w1 = *(const float4*)(rb + (((2 * q + 1) ^ sw) << 4));
      union { u16x8 u; bf16x8 b; } cv;
      cv.u[0] = f2bf_fast(w0.x); cv.u[1] = f2bf_fast(w0.y);
      cv.u[2] = f2bf_fast(w0.z); cv.u[3] = f2bf_fast(w0.w);
      cv.u[4] = f2bf_fast(w1.x); cv.u[5] = f2bf_fast(w1.y);
      cv.u[6] = f2bf_fast(w1.z); cv.u[7] = f2bf_fast(w1.w);
      bfr[j] = cv.b;
    }
#pragma unroll
    for (int i = 0; i < MI; i++)
#pragma unroll
      for (int j = 0; j < NJ; j++)
        acc[i][j] = __builtin_amdgcn_mfma_f32_16x16x32_bf16(af[i], bfr[j], acc[i][j], 0, 0, 0);
    __syncthreads();  // buffer reuse guard
  }

#pragma unroll
  for (int i = 0; i < MI; i++)
#pragma unroll
    for (int j = 0; j < NJ; j++) {
      int n = n0 + j * 16 + frow;
      int mb = m0 + i * 16 + (q << 2);
      if constexpr (EPI == 2) {
        float* pb = Pout + (size_t)sp * M * N;
#pragma unroll
        for (int r = 0; r < 4; r++)
          pb[(size_t)(mb + r) * N + n] = acc[i][j][r];
      } else if constexpr (EPI == 0) {
        float bb = bias[n];
#pragma unroll
        for (int r = 0; r < 4; r++) {
          float v = fmaxf(acc[i][j][r] + bb, 0.f);
          Hout[(size_t)(mb + r) * N + n] = f2bf(v);
        }
      } else {
        float bb = bias[n];
        int ch = n >> 7;
        float s = g2[ch] * rsqrtf(va2[ch] + EPSF);
        float mu = me2[ch], bt = be2[ch];
#pragma unroll
        for (int r = 0; r < 4; r++) {
          float v = fmaxf(acc[i][j][r] + bb, 0.f);
          size_t oi = (size_t)(mb + r) * N + n;
          v += res2[oi];
          Out[oi] = (v - mu) * s + bt;
        }
      }
    }
}

// ---------------- Reduce for G1: Hb = bf16(relu(P0+P1+b1))
__global__ __launch_bounds__(256) void red1_k(const float* __restrict__ P,
    const float* __restrict__ bias, unsigned short* __restrict__ H, int N, int MN) {
  int idx = blockIdx.x * 256 + threadIdx.x;  // one float4
  const float4* p = (const float4*)P;
  float4 a = p[idx];
  float4 b = p[idx + (MN >> 2)];
  int n = (idx << 2) & (N - 1);
  float4 bb = *(const float4*)(bias + n);
  ushort4 o;
  o.x = f2bf(fmaxf(a.x + b.x + bb.x, 0.f));
  o.y = f2bf(fmaxf(a.y + b.y + bb.y, 0.f));
  o.z = f2bf(fmaxf(a.z + b.z + bb.z, 0.f));
  o.w = f2bf(fmaxf(a.w + b.w + bb.w, 0.f));
  ((ushort4*)H)[idx] = o;
}

// ---------------- Reduce for G2: out = bn2(relu(sum4(P)+b2)+Xh)
__global__ __launch_bounds__(256) void red2_k(const float* __restrict__ P,
    const float* __restrict__ bias, const float* __restrict__ Xh,
    const float* __restrict__ g2, const float* __restrict__ be2,
    const float* __restrict__ me2, const float* __restrict__ va2,
    float* __restrict__ Out, int N, int MN) {
  int idx = blockIdx.x * 256 + threadIdx.x;
  const float4* p = (const float4*)P;
  int mn4 = MN >> 2;
  float4 a = p[idx], b = p[idx + mn4], c = p[idx + 2 * mn4], d = p[idx + 3 * mn4];
  int n = (idx << 2) & (N - 1);
  int ch = n >> 7;
  float4 bb = *(const float4*)(bias + n);
  float4 xh = ((const float4*)Xh)[idx];
  float s = g2[ch] * rsqrtf(va2[ch] + EPSF);
  float mu = me2[ch], bt = be2[ch];
  float4 o;
  o.x = (fmaxf(a.x + b.x + c.x + d.x + bb.x, 0.f) + xh.x - mu) * s + bt;
  o.y = (fmaxf(a.y + b.y + c.y + d.y + bb.y, 0.f) + xh.y - mu) * s + bt;
  o.z = (fmaxf(a.z + b.z + c.z + d.z + bb.z, 0.f) + xh.z - mu) * s + bt;
  o.w = (fmaxf(a.w + b.w + c.w + d.w + bb.w, 0.f) + xh.w - mu) * s + bt;
  ((float4*)Out)[idx] = o;
}

extern "C" void kernel_launch(void* const* d_in, const int* in_sizes, int n_in,
                              void* d_out, int out_size, void* d_ws, size_t ws_size,
                              hipStream_t stream) {
  const float* x  = (const float*)d_in[0];
  const float* Wq = (const float*)d_in[1];  const float* bq = (const float*)d_in[2];
  const float* Wk = (const float*)d_in[3];  const float* bk = (const float*)d_in[4];
  const float* Wv = (const float*)d_in[5];  const float* bv = (const float*)d_in[6];
  const float* Wo = (const float*)d_in[7];  const float* bo = (const float*)d_in[8];
  const float* g1 = (const float*)d_in[9];  const float* be1 = (const float*)d_in[10];
  const float* me1 = (const float*)d_in[11]; const float* va1 = (const float*)d_in[12];
  const float* W1 = (const float*)d_in[13]; const float* b1 = (const float*)d_in[14];
  const float* W2 = (const float*)d_in[15]; const float* b2 = (const float*)d_in[16];
  const float* g2 = (const float*)d_in[17]; const float* be2 = (const float*)d_in[18];
  const float* me2 = (const float*)d_in[19]; const float* va2 = (const float*)d_in[20];
  const int* idxs = (const int*)d_in[21];
  int U = in_sizes[21] / 512;
  float* out = (float*)d_out;

  char* ws = (char*)d_ws;
  float* QC = (float*)(ws);                    // 8 MB: Q, then Ctx
  float* Kb = (float*)(ws + (8u << 20));       // 8 MB: K, then h bf16
  float* Vb = (float*)(ws + (16u << 20));      // 8 MB: V, then f bf16
  float* YT = (float*)(ws + (24u << 20));      // 8 MB: xT, then Y
  float* Xh = (float*)(ws + (32u << 20));      // 8 MB: res2 fp32
  int* Mtop = (int*)(ws + (40u << 20));
  float* P1 = (float*)(ws + (48u << 20));      // 32 MB: G1 partials (2 x 16MB)
  float* P2 = (float*)(ws + (80u << 20));      // 32 MB: G2 partials (4 x 8MB)
  unsigned short* Fb = (unsigned short*)Vb;
  unsigned short* Hb = (unsigned short*)Kb;
  bool splitk = ws_size >= (size_t)(112u) * (1u << 20);

  dim3 b256(256);
  transpose_k<<<dim3(4, 512), b256, 0, stream>>>(x, YT, 16384, 128);
  qkv_k<<<dim3(128, 2), b256, 0, stream>>>(YT, Wq, bq, Wk, bk, Wv, bv, QC, Kb, Vb);
  topk_k<<<dim3(1024), dim3(512), 0, stream>>>(QC, Kb, idxs, Mtop, U);
  attn_k<<<dim3(1024), b256, 0, stream>>>(QC, Kb, Vb, Mtop, QC, U);
  oproj_k<<<dim3(128, 2), b256, 0, stream>>>(QC, Wo, bo, YT);
  bn1t_k<<<dim3(512, 4), b256, 0, stream>>>(YT, x, g1, be1, me1, va1, Xh, Fb);

  if (splitk) {
    // G1: tiles 128x64 (4m x 128n) x splitK2 = 1024 blocks (4/CU)
    gemm_ps<4, 2, 2><<<dim3(1024), b256, 0, stream>>>(
        Fb, W1, nullptr, 4096, 8192, 4, 16, 2, P1, 512,
        nullptr, nullptr, nullptr, nullptr, nullptr, nullptr, nullptr);
    red1_k<<<dim3(4096), b256, 0, stream>>>(P1, b1, Hb, 8192, 512 * 8192);
    // G2: tiles 128x64 (4m x 64n) x splitK4 = 1024 blocks (4/CU)
    gemm_ps<4, 2, 2><<<dim3(1024), b256, 0, stream>>>(
        Hb, W2, nullptr, 8192, 4096, 4, 8, 4, P2, 512,
        nullptr, nullptr, nullptr, nullptr, nullptr, nullptr, nullptr);
    red2_k<<<dim3(2048), b256, 0, stream>>>(P2, b2, Xh, g2, be2, me2, va2, out,
                                            4096, 512 * 4096);
  } else {
    gemm_ps<4, 2, 0><<<dim3(512), b256, 0, stream>>>(
        Fb, W1, b1, 4096, 8192, 4, 16, 1, nullptr, 512,
        Hb, nullptr, nullptr, nullptr, nullptr, nullptr, nullptr);
    gemm_ps<4, 2, 1><<<dim3(256), b256, 0, stream>>>(
        Hb, W2, b2, 8192, 4096, 4, 8, 1, nullptr, 512,
        nullptr, Xh, g2, be2, me2, va2, out);
  }
}

// Round 6
// 589.967 us; speedup vs baseline: 1.6169x; 1.0684x over previous
//
#include <hip/hip_runtime.h>
#include <stdint.h>

#define EPSF 1e-5f
#define NEG_INF (-1e30f)

typedef float f32x4 __attribute__((ext_vector_type(4)));
typedef __bf16 bf16x8 __attribute__((ext_vector_type(8)));
typedef unsigned short u16x8 __attribute__((ext_vector_type(8)));

typedef __attribute__((address_space(3))) unsigned char* as3_ptr;
typedef const __attribute__((address_space(1))) unsigned char* as1_ptr;

__device__ __forceinline__ void async16(const void* g, void* l) {
  __builtin_amdgcn_global_load_lds((as1_ptr)g, (as3_ptr)l, 16, 0, 0);
}

__device__ __forceinline__ unsigned short f2bf(float f) {
  union { float f; unsigned int u; } v; v.f = f;
  unsigned int r = v.u + 0x7FFFu + ((v.u >> 16) & 1u);
  return (unsigned short)(r >> 16);
}
__device__ __forceinline__ unsigned short f2bf_fast(float f) {
  union { float f; unsigned int u; } v; v.f = f;
  return (unsigned short)((v.u + 0x8000u) >> 16);
}

// ---------------- T0: generic 32x32 transpose
__global__ __launch_bounds__(256) void transpose_k(const float* __restrict__ src,
                                                   float* __restrict__ dst, int R, int C) {
  __shared__ float tl[32][33];
  int tx = threadIdx.x & 31, ty = threadIdx.x >> 5;
  int c0 = blockIdx.x * 32, r0 = blockIdx.y * 32;
#pragma unroll
  for (int i = 0; i < 4; i++)
    tl[ty + i * 8][tx] = src[(size_t)(r0 + ty + i * 8) * C + c0 + tx];
  __syncthreads();
#pragma unroll
  for (int i = 0; i < 4; i++)
    dst[(size_t)(c0 + ty + i * 8) * R + r0 + tx] = tl[tx][ty + i * 8];
}

// ---------------- A1: QKV projection
__global__ __launch_bounds__(256) void qkv_k(const float* __restrict__ xT,
    const float* __restrict__ Wq, const float* __restrict__ bq,
    const float* __restrict__ Wk, const float* __restrict__ bk,
    const float* __restrict__ Wv, const float* __restrict__ bv,
    float* __restrict__ Q, float* __restrict__ Kq, float* __restrict__ Vq) {
  __shared__ float xs[64 * 33];
  __shared__ float wq[32 * 33], wk[32 * 33], wvs[32 * 33];
  __shared__ float bqs[32], bks[32], bvs[32];
  int tid = threadIdx.x;
  int a = blockIdx.x;
  int tbase = blockIdx.y * 256;
#pragma unroll
  for (int i = 0; i < 4; i++) {
    int e = i * 256 + tid; int r = e >> 5, c = e & 31;
    wq[r * 33 + c] = Wq[e]; wk[r * 33 + c] = Wk[e]; wvs[r * 33 + c] = Wv[e];
  }
  if (tid < 32) { bqs[tid] = bq[tid]; bks[tid] = bk[tid]; bvs[tid] = bv[tid]; }
  int tl = tid & 63, rg = tid >> 6;
  for (int ch = 0; ch < 4; ch++) {
    __syncthreads();
#pragma unroll
    for (int i = 0; i < 8; i++) {
      int e = i * 256 + tid; int r = e >> 5, c = e & 31;
      xs[r * 33 + c] = xT[(size_t)a * 16384 + (size_t)(tbase + ch * 64) * 32 + e];
    }
    __syncthreads();
    float qa[8], ka[8], va[8];
#pragma unroll
    for (int r8 = 0; r8 < 8; r8++) {
      int r = rg * 8 + r8; qa[r8] = bqs[r]; ka[r8] = bks[r]; va[r8] = bvs[r];
    }
    for (int c = 0; c < 32; c++) {
      float xv = xs[tl * 33 + c];
#pragma unroll
      for (int r8 = 0; r8 < 8; r8++) {
        int r = rg * 8 + r8;
        qa[r8] += xv * wq[r * 33 + c];
        ka[r8] += xv * wk[r * 33 + c];
        va[r8] += xv * wvs[r * 33 + c];
      }
    }
    int t = tbase + ch * 64 + tl;
#pragma unroll
    for (int r8 = 0; r8 < 8; r8++) {
      int r = rg * 8 + r8;
      size_t o = (size_t)a * 16384 + (size_t)r * 512 + t;
      Q[o] = qa[r8]; Kq[o] = ka[r8]; Vq[o] = va[r8];
    }
  }
}

// ---------------- A2: top-U selection
__global__ __launch_bounds__(512) void topk_k(const float* __restrict__ Q,
    const float* __restrict__ Kq, const int* __restrict__ idxs,
    int* __restrict__ Mtop, int U) {
  __shared__ float Ks[2048];
  __shared__ float Ml[512];
  __shared__ float rv[8];
  __shared__ int ri[8];
  int bh = blockIdx.x;
  int tid = threadIdx.x, lane = tid & 63, wv = tid >> 6;
  size_t base = (size_t)bh * 2048;
#pragma unroll
  for (int i = 0; i < 4; i++) Ks[i * 512 + tid] = Kq[base + i * 512 + tid];
  float q0 = Q[base + tid], q1 = Q[base + 512 + tid];
  float q2 = Q[base + 1024 + tid], q3 = Q[base + 1536 + tid];
  __syncthreads();
  float mx = NEG_INF, sm = 0.f;
  for (int u = 0; u < U; u++) {
    int it = idxs[tid * U + u];
    it = min(max(it, 0), 511);
    float s = q0 * Ks[it] + q1 * Ks[512 + it] + q2 * Ks[1024 + it] + q3 * Ks[1536 + it];
    mx = fmaxf(mx, s); sm += s;
  }
  Ml[tid] = mx - sm * (1.f / 512.f);
  __syncthreads();
  for (int s_i = 0; s_i < U; s_i++) {
    float v = Ml[tid]; int ii = tid;
#pragma unroll
    for (int off = 32; off; off >>= 1) {
      float ov = __shfl_xor(v, off); int oi = __shfl_xor(ii, off);
      if (ov > v || (ov == v && oi < ii)) { v = ov; ii = oi; }
    }
    if (lane == 0) { rv[wv] = v; ri[wv] = ii; }
    __syncthreads();
    if (tid == 0) {
      float bv = rv[0]; int bi = ri[0];
      for (int w = 1; w < 8; w++)
        if (rv[w] > bv || (rv[w] == bv && ri[w] < bi)) { bv = rv[w]; bi = ri[w]; }
      Mtop[bh * U + s_i] = bi;
      Ml[bi] = NEG_INF;
    }
    __syncthreads();
  }
}

// ---------------- A3: attention core
__global__ __launch_bounds__(256) void attn_k(const float* __restrict__ Q,
    const float* __restrict__ Kq, const float* __restrict__ Vq,
    const int* __restrict__ Mtop, float* __restrict__ Ctx, int U) {
  __shared__ float Ks[2048];
  __shared__ float Vs[2048];
  __shared__ int mt[64];
  __shared__ float Qr[64][4];
  __shared__ float upd[64][4];
  int bh = blockIdx.x;
  int tid = threadIdx.x, lane = tid & 63, wv = tid >> 6;
  size_t base = (size_t)bh * 2048;
#pragma unroll
  for (int i = 0; i < 8; i++) {
    Ks[i * 256 + tid] = Kq[base + i * 256 + tid];
    Vs[i * 256 + tid] = Vq[base + i * 256 + tid];
  }
  if (tid < U) mt[tid] = Mtop[bh * U + tid];
  __syncthreads();
  if (tid < 4 * U) { int u = tid >> 2, d = tid & 3; Qr[u][d] = Q[base + d * 512 + mt[u]]; }
  __syncthreads();
  for (int u = wv; u < U; u += 4) {
    int mrow = mt[u];
    float q0 = Qr[u][0], q1 = Qr[u][1], q2 = Qr[u][2], q3 = Qr[u][3];
    float sv[8]; float lmax = NEG_INF;
#pragma unroll
    for (int jj = 0; jj < 8; jj++) {
      int k = jj * 64 + lane;
      float s = NEG_INF;
      if (k <= mrow)
        s = 0.5f * (q0 * Ks[k] + q1 * Ks[512 + k] + q2 * Ks[1024 + k] + q3 * Ks[1536 + k]);
      sv[jj] = s; lmax = fmaxf(lmax, s);
    }
#pragma unroll
    for (int off = 32; off; off >>= 1) lmax = fmaxf(lmax, __shfl_xor(lmax, off));
    float ls = 0.f, p0 = 0.f, p1 = 0.f, p2 = 0.f, p3 = 0.f;
#pragma unroll
    for (int jj = 0; jj < 8; jj++) {
      int k = jj * 64 + lane;
      if (k <= mrow) {
        float p = __expf(sv[jj] - lmax);
        ls += p; p0 += p * Vs[k]; p1 += p * Vs[512 + k];
        p2 += p * Vs[1024 + k]; p3 += p * Vs[1536 + k];
      }
    }
#pragma unroll
    for (int off = 32; off; off >>= 1) {
      ls += __shfl_xor(ls, off); p0 += __shfl_xor(p0, off); p1 += __shfl_xor(p1, off);
      p2 += __shfl_xor(p2, off); p3 += __shfl_xor(p3, off);
    }
    if (lane == 0) {
      float inv = 1.f / ls;
      upd[u][0] = p0 * inv; upd[u][1] = p1 * inv; upd[u][2] = p2 * inv; upd[u][3] = p3 * inv;
    }
  }
  __syncthreads();
  {
    float v[8];
    int b0 = wv * 512 + lane * 8;
#pragma unroll
    for (int q = 0; q < 8; q++) v[q] = Vs[b0 + q];
#pragma unroll
    for (int q = 1; q < 8; q++) v[q] += v[q - 1];
    float x = v[7];
    for (int off = 1; off < 64; off <<= 1) {
      float y = __shfl_up(x, off);
      if (lane >= off) x += y;
    }
    float excl = x - v[7];
#pragma unroll
    for (int q = 0; q < 8; q++) Vs[b0 + q] = v[q] + excl;
  }
  __syncthreads();
  if (tid < 4 * U) { int u = tid >> 2, d = tid & 3; Vs[d * 512 + mt[u]] = upd[u][d]; }
  __syncthreads();
#pragma unroll
  for (int i = 0; i < 8; i++) Ctx[base + i * 256 + tid] = Vs[i * 256 + tid];
}

// ---------------- A4: out-projection
__global__ __launch_bounds__(256) void oproj_k(const float* __restrict__ Ctx,
    const float* __restrict__ Wo, const float* __restrict__ bo, float* __restrict__ Y) {
  __shared__ float cs[32 * 256];
  __shared__ float wo[32 * 33];
  __shared__ float bos[32];
  int tid = threadIdx.x;
  int a = blockIdx.x, t0 = blockIdx.y * 256;
#pragma unroll
  for (int i = 0; i < 4; i++) {
    int e = i * 256 + tid; int r = e >> 5, c = e & 31;
    wo[r * 33 + c] = Wo[e];
  }
  if (tid < 32) bos[tid] = bo[tid];
#pragma unroll
  for (int i = 0; i < 32; i++) {
    int e = i * 256 + tid; int row = e >> 8, col = e & 255;
    cs[e] = Ctx[(size_t)a * 16384 + (size_t)row * 512 + t0 + col];
  }
  __syncthreads();
  int rl = tid & 31, tw = tid >> 5;
  for (int ti = 0; ti < 32; ti++) {
    int t = ti * 8 + tw;
    float acc = bos[rl];
#pragma unroll
    for (int rp = 0; rp < 32; rp++) acc += cs[rp * 256 + t] * wo[rl * 33 + rp];
    Y[(size_t)a * 16384 + (size_t)(t0 + t) * 32 + rl] = acc;
  }
}

// ---------------- T1: transpose + relu + res1 + bn1 -> Xh fp32 + f bf16
__global__ __launch_bounds__(256) void bn1t_k(const float* __restrict__ Y,
    const float* __restrict__ x, const float* __restrict__ g1, const float* __restrict__ be1,
    const float* __restrict__ me1, const float* __restrict__ va1,
    float* __restrict__ Xh, unsigned short* __restrict__ Fb) {
  __shared__ float tl[32][33];
  int tx = threadIdx.x & 31, ty = threadIdx.x >> 5;
  int c0 = blockIdx.x * 32;
  int r0 = blockIdx.y * 32;
#pragma unroll
  for (int i = 0; i < 4; i++)
    tl[ty + i * 8][tx] = Y[(size_t)(r0 + ty + i * 8) * 16384 + c0 + tx];
  __syncthreads();
#pragma unroll
  for (int i = 0; i < 4; i++) {
    int m = c0 + ty + i * 8;
    int a = r0 + tx;
    float v = tl[tx][ty + i * 8];
    int ch = m & 31;
    size_t oi = (size_t)m * 128 + a;
    float val = fmaxf(v, 0.f) + x[oi];
    float s = g1[ch] * rsqrtf(va1[ch] + EPSF);
    float res = (val - me1[ch]) * s + be1[ch];
    Xh[oi] = res;
    Fb[oi] = f2bf(res);
  }
}

// ---------------- W fp32 -> bf16 (one-time per GEMM, memory-bound)
__global__ __launch_bounds__(256) void wcvt_k(const float* __restrict__ W,
    unsigned short* __restrict__ Wb, int n4) {
  int stride = gridDim.x * 256;
  for (int idx = blockIdx.x * 256 + threadIdx.x; idx < n4; idx += stride) {
    float4 w = ((const float4*)W)[idx];
    ushort4 o;
    o.x = f2bf(w.x); o.y = f2bf(w.y); o.z = f2bf(w.z); o.w = f2bf(w.w);
    ((ushort4*)Wb)[idx] = o;
  }
}

// ---------------- All-bf16 m97-tile GEMM with split-K partials.
// C[m][n] = sum_k A[m][k]*B[n][k], both bf16 [.][K]. 128x128 tile, 16KB LDS,
// 16 MFMA/wave-iter, 2-barrier K-loop. Writes fp32 partial to P + sp*M*N.
__global__ __launch_bounds__(256, 3) void gemm_bf(
    const unsigned short* __restrict__ A, const unsigned short* __restrict__ B,
    int K, int N, int MT, int NPX, int SPLITK, float* __restrict__ P, int M) {
  __shared__ unsigned char lds[16384];  // A 8KB | B 8KB
  int tid = threadIdx.x;
  int lane = tid & 63, wv = tid >> 6;
  int wm = wv >> 1, wn = wv & 1;
  int lin = blockIdx.x;
  int xcd = lin & 7, slot = lin >> 3;
  int tilesPerSp = MT * NPX;
  int sp = slot / tilesPerSp;
  int rem = slot % tilesPerSp;
  int mt = rem % MT;
  int nt = xcd * NPX + rem / MT;
  int mtile0 = mt * 128, ntile0 = nt * 128;
  int m0 = mtile0 + wm * 64, n0 = ntile0 + wn * 64;
  int frow = lane & 15, q = lane >> 4;

  int nk = K / (32 * SPLITK);
  int kbase = sp * (K / SPLITK);

  f32x4 acc[4][4];
#pragma unroll
  for (int i = 0; i < 4; i++)
#pragma unroll
    for (int j = 0; j < 4; j++) { f32x4 z = {0.f, 0.f, 0.f, 0.f}; acc[i][j] = z; }

  for (int k = 0; k < nk; k++) {
    int ks = kbase + k * 32;
#pragma unroll
    for (int i = 0; i < 2; i++) {
      int e = i * 256 + tid;
      int row = e >> 2;
      int g = (e & 3) ^ ((row >> 1) & 3);
      async16(A + (size_t)(mtile0 + row) * K + ks + g * 8, lds + i * 4096 + wv * 1024);
    }
#pragma unroll
    for (int i = 0; i < 2; i++) {
      int e = i * 256 + tid;
      int row = e >> 2;
      int g = (e & 3) ^ ((row >> 1) & 3);
      async16(B + (size_t)(ntile0 + row) * K + ks + g * 8,
              lds + 8192 + i * 4096 + wv * 1024);
    }
    __syncthreads();  // compiler drains vmcnt before s_barrier
    bf16x8 af[4], bfr[4];
#pragma unroll
    for (int i = 0; i < 4; i++) {
      int row = wm * 64 + i * 16 + frow;
      af[i] = *(const bf16x8*)(lds + row * 64 + ((q ^ ((row >> 1) & 3)) << 4));
    }
#pragma unroll
    for (int j = 0; j < 4; j++) {
      int row = wn * 64 + j * 16 + frow;
      bfr[j] = *(const bf16x8*)(lds + 8192 + row * 64 + ((q ^ ((row >> 1) & 3)) << 4));
    }
#pragma unroll
    for (int i = 0; i < 4; i++)
#pragma unroll
      for (int j = 0; j < 4; j++)
        acc[i][j] = __builtin_amdgcn_mfma_f32_16x16x32_bf16(af[i], bfr[j], acc[i][j], 0, 0, 0);
    __syncthreads();  // buffer reuse guard
  }

  float* pb = P + (size_t)sp * M * N;
#pragma unroll
  for (int i = 0; i < 4; i++)
#pragma unroll
    for (int j = 0; j < 4; j++) {
      int n = n0 + j * 16 + frow;
      int mb = m0 + i * 16 + (q << 2);
#pragma unroll
      for (int r = 0; r < 4; r++)
        pb[(size_t)(mb + r) * N + n] = acc[i][j][r];
    }
}

// ---------------- round-5 GEMM (fp32 B), kept for small-ws fallback tiers
template <int MI, int NJ, int EPI>
__global__ __launch_bounds__(256) void gemm_ps(
    const unsigned short* __restrict__ A, const float* __restrict__ Bw,
    const float* __restrict__ bias, int K, int N, int MT, int NPX, int SPLITK,
    float* __restrict__ Pout, int M,
    unsigned short* __restrict__ Hout, const float* __restrict__ res2,
    const float* __restrict__ g2, const float* __restrict__ be2,
    const float* __restrict__ me2, const float* __restrict__ va2,
    float* __restrict__ Out) {
  constexpr int BM = MI * 32;
  constexpr int BN = NJ * 32;
  constexpr int ABYTES = BM * 32 * 2;
  constexpr int BBYTES = BN * 32 * 4;
  constexpr int SA = ABYTES / 4096;
  constexpr int SB = BBYTES / 4096;
  __shared__ unsigned char lds[ABYTES + BBYTES];
  int tid = threadIdx.x;
  int lane = tid & 63, wv = tid >> 6;
  int wm = wv >> 1, wn = wv & 1;
  int lin = blockIdx.x;
  int xcd = lin & 7, slot = lin >> 3;
  int tilesPerSp = MT * NPX;
  int sp = slot / tilesPerSp;
  int rem = slot % tilesPerSp;
  int mt = rem % MT;
  int nt = xcd * NPX + rem / MT;
  int m0 = mt * BM + wm * (BM / 2);
  int n0 = nt * BN + wn * (BN / 2);
  int frow = lane & 15, q = lane >> 4;
  int nk = K / (32 * SPLITK);
  int kbase = sp * (K / SPLITK);
  f32x4 acc[MI][NJ];
#pragma unroll
  for (int i = 0; i < MI; i++)
#pragma unroll
    for (int j = 0; j < NJ; j++) { f32x4 z = {0.f, 0.f, 0.f, 0.f}; acc[i][j] = z; }
  int mtile0 = mt * BM, ntile0 = nt * BN;
  for (int k = 0; k < nk; k++) {
    int ks = kbase + k * 32;
#pragma unroll
    for (int i = 0; i < SA; i++) {
      int e = i * 256 + tid;
      int row = e >> 2;
      int g = (e & 3) ^ ((row >> 1) & 3);
      async16(A + (size_t)(mtile0 + row) * K + ks + g * 8, lds + i * 4096 + wv * 1024);
    }
#pragma unroll
    for (int i = 0; i < SB; i++) {
      int e = i * 256 + tid;
      int row = e >> 3;
      int g = (e & 7) ^ (row & 7);
      async16(Bw + (size_t)(ntile0 + row) * K + ks + g * 4,
              lds + ABYTES + i * 4096 + wv * 1024);
    }
    __syncthreads();
    bf16x8 af[MI];
    bf16x8 bfr[NJ];
#pragma unroll
    for (int i = 0; i < MI; i++) {
      int row = wm * (BM / 2) + i * 16 + frow;
      af[i] = *(const bf16x8*)(lds + row * 64 + ((q ^ ((row >> 1) & 3)) << 4));
    }
#pragma unroll
    for (int j = 0; j < NJ; j++) {
      int row = wn * (BN / 2) + j * 16 + frow;
      const unsigned char* rb = lds + ABYTES + row * 128;
      int sw = row & 7;
      float4 w0 = *(const float4*)(rb + (((2 * q + 0) ^ sw) << 4));
      float4 w1 = *(const float4*)(rb + (((2 * q + 1) ^ sw) << 4));
      union { u16x8 u; bf16x8 b; } cv;
      cv.u[0] = f2bf_fast(w0.x); cv.u[1] = f2bf_fast(w0.y);
      cv.u[2] = f2bf_fast(w0.z); cv.u[3] = f2bf_fast(w0.w);
      cv.u[4] = f2bf_fast(w1.x); cv.u[5] = f2bf_fast(w1.y);
      cv.u[6] = f2bf_fast(w1.z); cv.u[7] = f2bf_fast(w1.w);
      bfr[j] = cv.b;
    }
#pragma unroll
    for (int i = 0; i < MI; i++)
#pragma unroll
      for (int j = 0; j < NJ; j++)
        acc[i][j] = __builtin_amdgcn_mfma_f32_16x16x32_bf16(af[i], bfr[j], acc[i][j], 0, 0, 0);
    __syncthreads();
  }
#pragma unroll
  for (int i = 0; i < MI; i++)
#pragma unroll
    for (int j = 0; j < NJ; j++) {
      int n = n0 + j * 16 + frow;
      int mb = m0 + i * 16 + (q << 2);
      if constexpr (EPI == 2) {
        float* pb = Pout + (size_t)sp * M * N;
#pragma unroll
        for (int r = 0; r < 4; r++)
          pb[(size_t)(mb + r) * N + n] = acc[i][j][r];
      } else if constexpr (EPI == 0) {
        float bb = bias[n];
#pragma unroll
        for (int r = 0; r < 4; r++) {
          float v = fmaxf(acc[i][j][r] + bb, 0.f);
          Hout[(size_t)(mb + r) * N + n] = f2bf(v);
        }
      } else {
        float bb = bias[n];
        int ch = n >> 7;
        float s = g2[ch] * rsqrtf(va2[ch] + EPSF);
        float mu = me2[ch], bt = be2[ch];
#pragma unroll
        for (int r = 0; r < 4; r++) {
          float v = fmaxf(acc[i][j][r] + bb, 0.f);
          size_t oi = (size_t)(mb + r) * N + n;
          v += res2[oi];
          Out[oi] = (v - mu) * s + bt;
        }
      }
    }
}

// ---------------- split-K reduce. EPI 0: bf16(relu(sum+bias)) -> H.
// EPI 1: bn2(relu(sum+bias)+Xh) -> Out.
template <int EPI>
__global__ __launch_bounds__(256) void red_k(const float* __restrict__ P, int SP,
    const float* __restrict__ bias, const float* __restrict__ Xh,
    const float* __restrict__ g2, const float* __restrict__ be2,
    const float* __restrict__ me2, const float* __restrict__ va2,
    unsigned short* __restrict__ H, float* __restrict__ Out, int N, int MN) {
  int idx = blockIdx.x * 256 + threadIdx.x;
  const float4* p = (const float4*)P;
  int mn4 = MN >> 2;
  float4 s = p[idx];
  for (int sp = 1; sp < SP; sp++) {
    float4 t = p[idx + (size_t)sp * mn4];
    s.x += t.x; s.y += t.y; s.z += t.z; s.w += t.w;
  }
  int n = (idx << 2) & (N - 1);
  float4 bb = *(const float4*)(bias + n);
  if constexpr (EPI == 0) {
    ushort4 o;
    o.x = f2bf(fmaxf(s.x + bb.x, 0.f));
    o.y = f2bf(fmaxf(s.y + bb.y, 0.f));
    o.z = f2bf(fmaxf(s.z + bb.z, 0.f));
    o.w = f2bf(fmaxf(s.w + bb.w, 0.f));
    ((ushort4*)H)[idx] = o;
  } else {
    int ch = n >> 7;
    float sc = g2[ch] * rsqrtf(va2[ch] + EPSF);
    float mu = me2[ch], bt = be2[ch];
    float4 xh = ((const float4*)Xh)[idx];
    float4 o;
    o.x = (fmaxf(s.x + bb.x, 0.f) + xh.x - mu) * sc + bt;
    o.y = (fmaxf(s.y + bb.y, 0.f) + xh.y - mu) * sc + bt;
    o.z = (fmaxf(s.z + bb.z, 0.f) + xh.z - mu) * sc + bt;
    o.w = (fmaxf(s.w + bb.w, 0.f) + xh.w - mu) * sc + bt;
    ((float4*)Out)[idx] = o;
  }
}

extern "C" void kernel_launch(void* const* d_in, const int* in_sizes, int n_in,
                              void* d_out, int out_size, void* d_ws, size_t ws_size,
                              hipStream_t stream) {
  const float* x  = (const float*)d_in[0];
  const float* Wq = (const float*)d_in[1];  const float* bq = (const float*)d_in[2];
  const float* Wk = (const float*)d_in[3];  const float* bk = (const float*)d_in[4];
  const float* Wv = (const float*)d_in[5];  const float* bv = (const float*)d_in[6];
  const float* Wo = (const float*)d_in[7];  const float* bo = (const float*)d_in[8];
  const float* g1 = (const float*)d_in[9];  const float* be1 = (const float*)d_in[10];
  const float* me1 = (const float*)d_in[11]; const float* va1 = (const float*)d_in[12];
  const float* W1 = (const float*)d_in[13]; const float* b1 = (const float*)d_in[14];
  const float* W2 = (const float*)d_in[15]; const float* b2 = (const float*)d_in[16];
  const float* g2 = (const float*)d_in[17]; const float* be2 = (const float*)d_in[18];
  const float* me2 = (const float*)d_in[19]; const float* va2 = (const float*)d_in[20];
  const int* idxs = (const int*)d_in[21];
  int U = in_sizes[21] / 512;
  float* out = (float*)d_out;

  char* ws = (char*)d_ws;
  float* QC = (float*)(ws);                    // 8 MB: Q, then Ctx
  float* Kb = (float*)(ws + (8u << 20));       // 8 MB: K, then h bf16
  float* Vb = (float*)(ws + (16u << 20));      // 8 MB: V, then f bf16
  float* YT = (float*)(ws + (24u << 20));      // 8 MB: xT, then Y
  float* Xh = (float*)(ws + (32u << 20));      // 8 MB: res2 fp32
  int* Mtop = (int*)(ws + (40u << 20));
  unsigned short* Fb = (unsigned short*)Vb;
  unsigned short* Hb = (unsigned short*)Kb;
  // Tier A (ws >= 176 MB): Wb 64 MB @48 (W1b then W2b), P 64 MB @112 (P1 then P2)
  unsigned short* Wb = (unsigned short*)(ws + (48u << 20));
  float* PA = (float*)(ws + (112u << 20));
  // Tier B (ws >= 112 MB): round-5 layout
  float* P1 = (float*)(ws + (48u << 20));
  float* P2 = (float*)(ws + (80u << 20));
  bool tierA = ws_size >= (size_t)176 * (1u << 20);
  bool tierB = !tierA && ws_size >= (size_t)112 * (1u << 20);

  dim3 b256(256);
  transpose_k<<<dim3(4, 512), b256, 0, stream>>>(x, YT, 16384, 128);
  qkv_k<<<dim3(128, 2), b256, 0, stream>>>(YT, Wq, bq, Wk, bk, Wv, bv, QC, Kb, Vb);
  topk_k<<<dim3(1024), dim3(512), 0, stream>>>(QC, Kb, idxs, Mtop, U);
  attn_k<<<dim3(1024), b256, 0, stream>>>(QC, Kb, Vb, Mtop, QC, U);
  oproj_k<<<dim3(128, 2), b256, 0, stream>>>(QC, Wo, bo, YT);
  bn1t_k<<<dim3(512, 4), b256, 0, stream>>>(YT, x, g1, be1, me1, va1, Xh, Fb);

  if (tierA) {
    // W1 -> bf16
    wcvt_k<<<dim3(2048), b256, 0, stream>>>(W1, Wb, (8192 * 4096) / 4);
    // G1: 128x128 tiles, MT=4, NPX=8, splitK=4 -> 1024 blocks
    gemm_bf<<<dim3(1024), b256, 0, stream>>>(Fb, Wb, 4096, 8192, 4, 8, 4, PA, 512);
    red_k<0><<<dim3(4096), b256, 0, stream>>>(PA, 4, b1, nullptr, nullptr, nullptr,
                                              nullptr, nullptr, Hb, nullptr, 8192,
                                              512 * 8192);
    // W2 -> bf16 (overwrites W1b; W1b dead)
    wcvt_k<<<dim3(2048), b256, 0, stream>>>(W2, Wb, (4096 * 8192) / 4);
    // G2: 128x128 tiles, MT=4, NPX=4, splitK=8 -> 1024 blocks
    gemm_bf<<<dim3(1024), b256, 0, stream>>>(Hb, Wb, 8192, 4096, 4, 4, 8, PA, 512);
    red_k<1><<<dim3(2048), b256, 0, stream>>>(PA, 8, b2, Xh, g2, be2, me2, va2,
                                              nullptr, out, 4096, 512 * 4096);
  } else if (tierB) {
    gemm_ps<4, 2, 2><<<dim3(1024), b256, 0, stream>>>(
        Fb, W1, nullptr, 4096, 8192, 4, 16, 2, P1, 512,
        nullptr, nullptr, nullptr, nullptr, nullptr, nullptr, nullptr);
    red_k<0><<<dim3(4096), b256, 0, stream>>>(P1, 2, b1, nullptr, nullptr, nullptr,
                                              nullptr, nullptr, Hb, nullptr, 8192,
                                              512 * 8192);
    gemm_ps<4, 2, 2><<<dim3(1024), b256, 0, stream>>>(
        Hb, W2, nullptr, 8192, 4096, 4, 8, 4, P2, 512,
        nullptr, nullptr, nullptr, nullptr, nullptr, nullptr, nullptr);
    red_k<1><<<dim3(2048), b256, 0, stream>>>(P2, 4, b2, Xh, g2, be2, me2, va2,
                                              nullptr, out, 4096, 512 * 4096);
  } else {
    gemm_ps<4, 2, 0><<<dim3(512), b256, 0, stream>>>(
        Fb, W1, b1, 4096, 8192, 4, 16, 1, nullptr, 512,
        Hb, nullptr, nullptr, nullptr, nullptr, nullptr, nullptr);
    gemm_ps<4, 2, 1><<<dim3(256), b256, 0, stream>>>(
        Hb, W2, b2, 8192, 4096, 4, 8, 1, nullptr, 512,
        nullptr, Xh, g2, be2, me2, va2, out);
  }
}

// Round 7
// 552.278 us; speedup vs baseline: 1.7272x; 1.0682x over previous
//
#include <hip/hip_runtime.h>
#include <stdint.h>

#define EPSF 1e-5f
#define NEG_INF (-1e30f)

typedef float f32x4 __attribute__((ext_vector_type(4)));
typedef __bf16 bf16x8 __attribute__((ext_vector_type(8)));
typedef unsigned short u16x8 __attribute__((ext_vector_type(8)));

typedef __attribute__((address_space(3))) unsigned char* as3_ptr;
typedef const __attribute__((address_space(1))) unsigned char* as1_ptr;

__device__ __forceinline__ void async16(const void* g, void* l) {
  __builtin_amdgcn_global_load_lds((as1_ptr)g, (as3_ptr)l, 16, 0, 0);
}

__device__ __forceinline__ unsigned short f2bf(float f) {
  union { float f; unsigned int u; } v; v.f = f;
  unsigned int r = v.u + 0x7FFFu + ((v.u >> 16) & 1u);
  return (unsigned short)(r >> 16);
}
__device__ __forceinline__ unsigned short f2bf_fast(float f) {
  union { float f; unsigned int u; } v; v.f = f;
  return (unsigned short)((v.u + 0x8000u) >> 16);
}

// ---------------- T0: generic 32x32 transpose
__global__ __launch_bounds__(256) void transpose_k(const float* __restrict__ src,
                                                   float* __restrict__ dst, int R, int C) {
  __shared__ float tl[32][33];
  int tx = threadIdx.x & 31, ty = threadIdx.x >> 5;
  int c0 = blockIdx.x * 32, r0 = blockIdx.y * 32;
#pragma unroll
  for (int i = 0; i < 4; i++)
    tl[ty + i * 8][tx] = src[(size_t)(r0 + ty + i * 8) * C + c0 + tx];
  __syncthreads();
#pragma unroll
  for (int i = 0; i < 4; i++)
    dst[(size_t)(c0 + ty + i * 8) * R + r0 + tx] = tl[tx][ty + i * 8];
}

// ---------------- A1: QKV projection
__global__ __launch_bounds__(256) void qkv_k(const float* __restrict__ xT,
    const float* __restrict__ Wq, const float* __restrict__ bq,
    const float* __restrict__ Wk, const float* __restrict__ bk,
    const float* __restrict__ Wv, const float* __restrict__ bv,
    float* __restrict__ Q, float* __restrict__ Kq, float* __restrict__ Vq) {
  __shared__ float xs[64 * 33];
  __shared__ float wq[32 * 33], wk[32 * 33], wvs[32 * 33];
  __shared__ float bqs[32], bks[32], bvs[32];
  int tid = threadIdx.x;
  int a = blockIdx.x;
  int tbase = blockIdx.y * 256;
#pragma unroll
  for (int i = 0; i < 4; i++) {
    int e = i * 256 + tid; int r = e >> 5, c = e & 31;
    wq[r * 33 + c] = Wq[e]; wk[r * 33 + c] = Wk[e]; wvs[r * 33 + c] = Wv[e];
  }
  if (tid < 32) { bqs[tid] = bq[tid]; bks[tid] = bk[tid]; bvs[tid] = bv[tid]; }
  int tl = tid & 63, rg = tid >> 6;
  for (int ch = 0; ch < 4; ch++) {
    __syncthreads();
#pragma unroll
    for (int i = 0; i < 8; i++) {
      int e = i * 256 + tid; int r = e >> 5, c = e & 31;
      xs[r * 33 + c] = xT[(size_t)a * 16384 + (size_t)(tbase + ch * 64) * 32 + e];
    }
    __syncthreads();
    float qa[8], ka[8], va[8];
#pragma unroll
    for (int r8 = 0; r8 < 8; r8++) {
      int r = rg * 8 + r8; qa[r8] = bqs[r]; ka[r8] = bks[r]; va[r8] = bvs[r];
    }
    for (int c = 0; c < 32; c++) {
      float xv = xs[tl * 33 + c];
#pragma unroll
      for (int r8 = 0; r8 < 8; r8++) {
        int r = rg * 8 + r8;
        qa[r8] += xv * wq[r * 33 + c];
        ka[r8] += xv * wk[r * 33 + c];
        va[r8] += xv * wvs[r * 33 + c];
      }
    }
    int t = tbase + ch * 64 + tl;
#pragma unroll
    for (int r8 = 0; r8 < 8; r8++) {
      int r = rg * 8 + r8;
      size_t o = (size_t)a * 16384 + (size_t)r * 512 + t;
      Q[o] = qa[r8]; Kq[o] = ka[r8]; Vq[o] = va[r8];
    }
  }
}

// ---------------- A2+A3 merged: rank-based top-U + attention core.
// Block = (a,h). 512 threads. Rank selection replaces 35 serial argmax rounds.
__global__ __launch_bounds__(512) void topattn_k(const float* __restrict__ Q,
    const float* __restrict__ Kq, const float* __restrict__ Vq,
    const int* __restrict__ idxs, float* __restrict__ Ctx, int U) {
  __shared__ float Ks[2048];
  __shared__ float Vs[2048];
  __shared__ float Ml[512];
  __shared__ int mt[64];
  __shared__ float Qr[64][4];
  __shared__ float upd[64][4];
  int bh = blockIdx.x;
  int tid = threadIdx.x, lane = tid & 63, wv = tid >> 6;
  size_t base = (size_t)bh * 2048;
#pragma unroll
  for (int i = 0; i < 4; i++) {
    Ks[i * 512 + tid] = Kq[base + i * 512 + tid];
    Vs[i * 512 + tid] = Vq[base + i * 512 + tid];
  }
  float q0 = Q[base + tid], q1 = Q[base + 512 + tid];
  float q2 = Q[base + 1024 + tid], q3 = Q[base + 1536 + tid];
  __syncthreads();
  // M = max_u(QK_sample) - mean(QK_sample)
  float mx = NEG_INF, sm = 0.f;
  for (int u = 0; u < U; u++) {
    int it = idxs[tid * U + u];
    it = min(max(it, 0), 511);
    float s = q0 * Ks[it] + q1 * Ks[512 + it] + q2 * Ks[1024 + it] + q3 * Ks[1536 + it];
    mx = fmaxf(mx, s); sm += s;
  }
  Ml[tid] = mx - sm * (1.f / 512.f);
  __syncthreads();
  // rank_i = #{j: Mj > Mi or (Mj==Mi and j<i)}; ranks unique; top-U iff rank<U
  float mi = Ml[tid];
  int rank = 0;
  for (int j0 = 0; j0 < 512; j0 += 4) {
    float4 m4 = *(const float4*)(Ml + j0);  // broadcast read, conflict-free
    rank += (m4.x > mi) || (m4.x == mi && (j0 + 0) < tid);
    rank += (m4.y > mi) || (m4.y == mi && (j0 + 1) < tid);
    rank += (m4.z > mi) || (m4.z == mi && (j0 + 2) < tid);
    rank += (m4.w > mi) || (m4.w == mi && (j0 + 3) < tid);
  }
  if (rank < U) mt[rank] = tid;
  __syncthreads();
  if (tid < 4 * U) { int u = tid >> 2, d = tid & 3; Qr[u][d] = Q[base + d * 512 + mt[u]]; }
  __syncthreads();
  // per-selected-row masked softmax + PV (one wave per row, rows strided by 8)
  for (int u = wv; u < U; u += 8) {
    int mrow = mt[u];
    float p0q = Qr[u][0], p1q = Qr[u][1], p2q = Qr[u][2], p3q = Qr[u][3];
    float sv[8]; float lmax = NEG_INF;
#pragma unroll
    for (int jj = 0; jj < 8; jj++) {
      int k = jj * 64 + lane;
      float s = NEG_INF;
      if (k <= mrow)
        s = 0.5f * (p0q * Ks[k] + p1q * Ks[512 + k] + p2q * Ks[1024 + k] + p3q * Ks[1536 + k]);
      sv[jj] = s; lmax = fmaxf(lmax, s);
    }
#pragma unroll
    for (int off = 32; off; off >>= 1) lmax = fmaxf(lmax, __shfl_xor(lmax, off));
    float ls = 0.f, p0 = 0.f, p1 = 0.f, p2 = 0.f, p3 = 0.f;
#pragma unroll
    for (int jj = 0; jj < 8; jj++) {
      int k = jj * 64 + lane;
      if (k <= mrow) {
        float p = __expf(sv[jj] - lmax);
        ls += p; p0 += p * Vs[k]; p1 += p * Vs[512 + k];
        p2 += p * Vs[1024 + k]; p3 += p * Vs[1536 + k];
      }
    }
#pragma unroll
    for (int off = 32; off; off >>= 1) {
      ls += __shfl_xor(ls, off); p0 += __shfl_xor(p0, off); p1 += __shfl_xor(p1, off);
      p2 += __shfl_xor(p2, off); p3 += __shfl_xor(p3, off);
    }
    if (lane == 0) {
      float inv = 1.f / ls;
      upd[u][0] = p0 * inv; upd[u][1] = p1 * inv; upd[u][2] = p2 * inv; upd[u][3] = p3 * inv;
    }
  }
  __syncthreads();
  // cumsum of V over t (waves 0..3, one per d)
  if (wv < 4) {
    float v[8];
    int b0 = wv * 512 + lane * 8;
#pragma unroll
    for (int q = 0; q < 8; q++) v[q] = Vs[b0 + q];
#pragma unroll
    for (int q = 1; q < 8; q++) v[q] += v[q - 1];
    float x = v[7];
    for (int off = 1; off < 64; off <<= 1) {
      float y = __shfl_up(x, off);
      if (lane >= off) x += y;
    }
    float excl = x - v[7];
#pragma unroll
    for (int q = 0; q < 8; q++) Vs[b0 + q] = v[q] + excl;
  }
  __syncthreads();
  if (tid < 4 * U) { int u = tid >> 2, d = tid & 3; Vs[d * 512 + mt[u]] = upd[u][d]; }
  __syncthreads();
#pragma unroll
  for (int i = 0; i < 4; i++) Ctx[base + i * 512 + tid] = Vs[i * 512 + tid];
}

// ---------------- A4: out-projection
__global__ __launch_bounds__(256) void oproj_k(const float* __restrict__ Ctx,
    const float* __restrict__ Wo, const float* __restrict__ bo, float* __restrict__ Y) {
  __shared__ float cs[32 * 256];
  __shared__ float wo[32 * 33];
  __shared__ float bos[32];
  int tid = threadIdx.x;
  int a = blockIdx.x, t0 = blockIdx.y * 256;
#pragma unroll
  for (int i = 0; i < 4; i++) {
    int e = i * 256 + tid; int r = e >> 5, c = e & 31;
    wo[r * 33 + c] = Wo[e];
  }
  if (tid < 32) bos[tid] = bo[tid];
#pragma unroll
  for (int i = 0; i < 32; i++) {
    int e = i * 256 + tid; int row = e >> 8, col = e & 255;
    cs[e] = Ctx[(size_t)a * 16384 + (size_t)row * 512 + t0 + col];
  }
  __syncthreads();
  int rl = tid & 31, tw = tid >> 5;
  for (int ti = 0; ti < 32; ti++) {
    int t = ti * 8 + tw;
    float acc = bos[rl];
#pragma unroll
    for (int rp = 0; rp < 32; rp++) acc += cs[rp * 256 + t] * wo[rl * 33 + rp];
    Y[(size_t)a * 16384 + (size_t)(t0 + t) * 32 + rl] = acc;
  }
}

// ---------------- T1: transpose + relu + res1 + bn1 -> Xh fp32 + f bf16
__global__ __launch_bounds__(256) void bn1t_k(const float* __restrict__ Y,
    const float* __restrict__ x, const float* __restrict__ g1, const float* __restrict__ be1,
    const float* __restrict__ me1, const float* __restrict__ va1,
    float* __restrict__ Xh, unsigned short* __restrict__ Fb) {
  __shared__ float tl[32][33];
  int tx = threadIdx.x & 31, ty = threadIdx.x >> 5;
  int c0 = blockIdx.x * 32;
  int r0 = blockIdx.y * 32;
#pragma unroll
  for (int i = 0; i < 4; i++)
    tl[ty + i * 8][tx] = Y[(size_t)(r0 + ty + i * 8) * 16384 + c0 + tx];
  __syncthreads();
#pragma unroll
  for (int i = 0; i < 4; i++) {
    int m = c0 + ty + i * 8;
    int a = r0 + tx;
    float v = tl[tx][ty + i * 8];
    int ch = m & 31;
    size_t oi = (size_t)m * 128 + a;
    float val = fmaxf(v, 0.f) + x[oi];
    float s = g1[ch] * rsqrtf(va1[ch] + EPSF);
    float res = (val - me1[ch]) * s + be1[ch];
    Xh[oi] = res;
    Fb[oi] = f2bf(res);
  }
}

// ---------------- W fp32 -> bf16 (one-time per GEMM, memory-bound)
__global__ __launch_bounds__(256) void wcvt_k(const float* __restrict__ W,
    unsigned short* __restrict__ Wb, int n4) {
  int stride = gridDim.x * 256;
  for (int idx = blockIdx.x * 256 + threadIdx.x; idx < n4; idx += stride) {
    float4 w = ((const float4*)W)[idx];
    ushort4 o;
    o.x = f2bf(w.x); o.y = f2bf(w.y); o.z = f2bf(w.z); o.w = f2bf(w.w);
    ((ushort4*)Wb)[idx] = o;
  }
}

// ---------------- All-bf16 m97-tile GEMM with split-K partials.
__global__ __launch_bounds__(256, 3) void gemm_bf(
    const unsigned short* __restrict__ A, const unsigned short* __restrict__ B,
    int K, int N, int MT, int NPX, int SPLITK, float* __restrict__ P, int M) {
  __shared__ unsigned char lds[16384];  // A 8KB | B 8KB
  int tid = threadIdx.x;
  int lane = tid & 63, wv = tid >> 6;
  int wm = wv >> 1, wn = wv & 1;
  int lin = blockIdx.x;
  int xcd = lin & 7, slot = lin >> 3;
  int tilesPerSp = MT * NPX;
  int sp = slot / tilesPerSp;
  int rem = slot % tilesPerSp;
  int mt = rem % MT;
  int nt = xcd * NPX + rem / MT;
  int mtile0 = mt * 128, ntile0 = nt * 128;
  int m0 = mtile0 + wm * 64, n0 = ntile0 + wn * 64;
  int frow = lane & 15, q = lane >> 4;

  int nk = K / (32 * SPLITK);
  int kbase = sp * (K / SPLITK);

  f32x4 acc[4][4];
#pragma unroll
  for (int i = 0; i < 4; i++)
#pragma unroll
    for (int j = 0; j < 4; j++) { f32x4 z = {0.f, 0.f, 0.f, 0.f}; acc[i][j] = z; }

  for (int k = 0; k < nk; k++) {
    int ks = kbase + k * 32;
#pragma unroll
    for (int i = 0; i < 2; i++) {
      int e = i * 256 + tid;
      int row = e >> 2;
      int g = (e & 3) ^ ((row >> 1) & 3);
      async16(A + (size_t)(mtile0 + row) * K + ks + g * 8, lds + i * 4096 + wv * 1024);
    }
#pragma unroll
    for (int i = 0; i < 2; i++) {
      int e = i * 256 + tid;
      int row = e >> 2;
      int g = (e & 3) ^ ((row >> 1) & 3);
      async16(B + (size_t)(ntile0 + row) * K + ks + g * 8,
              lds + 8192 + i * 4096 + wv * 1024);
    }
    __syncthreads();
    bf16x8 af[4], bfr[4];
#pragma unroll
    for (int i = 0; i < 4; i++) {
      int row = wm * 64 + i * 16 + frow;
      af[i] = *(const bf16x8*)(lds + row * 64 + ((q ^ ((row >> 1) & 3)) << 4));
    }
#pragma unroll
    for (int j = 0; j < 4; j++) {
      int row = wn * 64 + j * 16 + frow;
      bfr[j] = *(const bf16x8*)(lds + 8192 + row * 64 + ((q ^ ((row >> 1) & 3)) << 4));
    }
#pragma unroll
    for (int i = 0; i < 4; i++)
#pragma unroll
      for (int j = 0; j < 4; j++)
        acc[i][j] = __builtin_amdgcn_mfma_f32_16x16x32_bf16(af[i], bfr[j], acc[i][j], 0, 0, 0);
    __syncthreads();
  }

  float* pb = P + (size_t)sp * M * N;
#pragma unroll
  for (int i = 0; i < 4; i++)
#pragma unroll
    for (int j = 0; j < 4; j++) {
      int n = n0 + j * 16 + frow;
      int mb = m0 + i * 16 + (q << 2);
#pragma unroll
      for (int r = 0; r < 4; r++)
        pb[(size_t)(mb + r) * N + n] = acc[i][j][r];
    }
}

// ---------------- round-5 GEMM (fp32 B), kept for small-ws fallback tiers
template <int MI, int NJ, int EPI>
__global__ __launch_bounds__(256) void gemm_ps(
    const unsigned short* __restrict__ A, const float* __restrict__ Bw,
    const float* __restrict__ bias, int K, int N, int MT, int NPX, int SPLITK,
    float* __restrict__ Pout, int M,
    unsigned short* __restrict__ Hout, const float* __restrict__ res2,
    const float* __restrict__ g2, const float* __restrict__ be2,
    const float* __restrict__ me2, const float* __restrict__ va2,
    float* __restrict__ Out) {
  constexpr int BM = MI * 32;
  constexpr int BN = NJ * 32;
  constexpr int ABYTES = BM * 32 * 2;
  constexpr int BBYTES = BN * 32 * 4;
  constexpr int SA = ABYTES / 4096;
  constexpr int SB = BBYTES / 4096;
  __shared__ unsigned char lds[ABYTES + BBYTES];
  int tid = threadIdx.x;
  int lane = tid & 63, wv = tid >> 6;
  int wm = wv >> 1, wn = wv & 1;
  int lin = blockIdx.x;
  int xcd = lin & 7, slot = lin >> 3;
  int tilesPerSp = MT * NPX;
  int sp = slot / tilesPerSp;
  int rem = slot % tilesPerSp;
  int mt = rem % MT;
  int nt = xcd * NPX + rem / MT;
  int m0 = mt * BM + wm * (BM / 2);
  int n0 = nt * BN + wn * (BN / 2);
  int frow = lane & 15, q = lane >> 4;
  int nk = K / (32 * SPLITK);
  int kbase = sp * (K / SPLITK);
  f32x4 acc[MI][NJ];
#pragma unroll
  for (int i = 0; i < MI; i++)
#pragma unroll
    for (int j = 0; j < NJ; j++) { f32x4 z = {0.f, 0.f, 0.f, 0.f}; acc[i][j] = z; }
  int mtile0 = mt * BM, ntile0 = nt * BN;
  for (int k = 0; k < nk; k++) {
    int ks = kbase + k * 32;
#pragma unroll
    for (int i = 0; i < SA; i++) {
      int e = i * 256 + tid;
      int row = e >> 2;
      int g = (e & 3) ^ ((row >> 1) & 3);
      async16(A + (size_t)(mtile0 + row) * K + ks + g * 8, lds + i * 4096 + wv * 1024);
    }
#pragma unroll
    for (int i = 0; i < SB; i++) {
      int e = i * 256 + tid;
      int row = e >> 3;
      int g = (e & 7) ^ (row & 7);
      async16(Bw + (size_t)(ntile0 + row) * K + ks + g * 4,
              lds + ABYTES + i * 4096 + wv * 1024);
    }
    __syncthreads();
    bf16x8 af[MI];
    bf16x8 bfr[NJ];
#pragma unroll
    for (int i = 0; i < MI; i++) {
      int row = wm * (BM / 2) + i * 16 + frow;
      af[i] = *(const bf16x8*)(lds + row * 64 + ((q ^ ((row >> 1) & 3)) << 4));
    }
#pragma unroll
    for (int j = 0; j < NJ; j++) {
      int row = wn * (BN / 2) + j * 16 + frow;
      const unsigned char* rb = lds + ABYTES + row * 128;
      int sw = row & 7;
      float4 w0 = *(const float4*)(rb + (((2 * q + 0) ^ sw) << 4));
      float4 w1 = *(const float4*)(rb + (((2 * q + 1) ^ sw) << 4));
      union { u16x8 u; bf16x8 b; } cv;
      cv.u[0] = f2bf_fast(w0.x); cv.u[1] = f2bf_fast(w0.y);
      cv.u[2] = f2bf_fast(w0.z); cv.u[3] = f2bf_fast(w0.w);
      cv.u[4] = f2bf_fast(w1.x); cv.u[5] = f2bf_fast(w1.y);
      cv.u[6] = f2bf_fast(w1.z); cv.u[7] = f2bf_fast(w1.w);
      bfr[j] = cv.b;
    }
#pragma unroll
    for (int i = 0; i < MI; i++)
#pragma unroll
      for (int j = 0; j < NJ; j++)
        acc[i][j] = __builtin_amdgcn_mfma_f32_16x16x32_bf16(af[i], bfr[j], acc[i][j], 0, 0, 0);
    __syncthreads();
  }
#pragma unroll
  for (int i = 0; i < MI; i++)
#pragma unroll
    for (int j = 0; j < NJ; j++) {
      int n = n0 + j * 16 + frow;
      int mb = m0 + i * 16 + (q << 2);
      if constexpr (EPI == 2) {
        float* pb = Pout + (size_t)sp * M * N;
#pragma unroll
        for (int r = 0; r < 4; r++)
          pb[(size_t)(mb + r) * N + n] = acc[i][j][r];
      } else if constexpr (EPI == 0) {
        float bb = bias[n];
#pragma unroll
        for (int r = 0; r < 4; r++) {
          float v = fmaxf(acc[i][j][r] + bb, 0.f);
          Hout[(size_t)(mb + r) * N + n] = f2bf(v);
        }
      } else {
        float bb = bias[n];
        int ch = n >> 7;
        float s = g2[ch] * rsqrtf(va2[ch] + EPSF);
        float mu = me2[ch], bt = be2[ch];
#pragma unroll
        for (int r = 0; r < 4; r++) {
          float v = fmaxf(acc[i][j][r] + bb, 0.f);
          size_t oi = (size_t)(mb + r) * N + n;
          v += res2[oi];
          Out[oi] = (v - mu) * s + bt;
        }
      }
    }
}

// ---------------- split-K reduce. EPI 0: bf16(relu(sum+bias)) -> H.
// EPI 1: bn2(relu(sum+bias)+Xh) -> Out.
template <int EPI>
__global__ __launch_bounds__(256) void red_k(const float* __restrict__ P, int SP,
    const float* __restrict__ bias, const float* __restrict__ Xh,
    const float* __restrict__ g2, const float* __restrict__ be2,
    const float* __restrict__ me2, const float* __restrict__ va2,
    unsigned short* __restrict__ H, float* __restrict__ Out, int N, int MN) {
  int idx = blockIdx.x * 256 + threadIdx.x;
  const float4* p = (const float4*)P;
  int mn4 = MN >> 2;
  float4 s = p[idx];
  for (int sp = 1; sp < SP; sp++) {
    float4 t = p[idx + (size_t)sp * mn4];
    s.x += t.x; s.y += t.y; s.z += t.z; s.w += t.w;
  }
  int n = (idx << 2) & (N - 1);
  float4 bb = *(const float4*)(bias + n);
  if constexpr (EPI == 0) {
    ushort4 o;
    o.x = f2bf(fmaxf(s.x + bb.x, 0.f));
    o.y = f2bf(fmaxf(s.y + bb.y, 0.f));
    o.z = f2bf(fmaxf(s.z + bb.z, 0.f));
    o.w = f2bf(fmaxf(s.w + bb.w, 0.f));
    ((ushort4*)H)[idx] = o;
  } else {
    int ch = n >> 7;
    float sc = g2[ch] * rsqrtf(va2[ch] + EPSF);
    float mu = me2[ch], bt = be2[ch];
    float4 xh = ((const float4*)Xh)[idx];
    float4 o;
    o.x = (fmaxf(s.x + bb.x, 0.f) + xh.x - mu) * sc + bt;
    o.y = (fmaxf(s.y + bb.y, 0.f) + xh.y - mu) * sc + bt;
    o.z = (fmaxf(s.z + bb.z, 0.f) + xh.z - mu) * sc + bt;
    o.w = (fmaxf(s.w + bb.w, 0.f) + xh.w - mu) * sc + bt;
    ((float4*)Out)[idx] = o;
  }
}

extern "C" void kernel_launch(void* const* d_in, const int* in_sizes, int n_in,
                              void* d_out, int out_size, void* d_ws, size_t ws_size,
                              hipStream_t stream) {
  const float* x  = (const float*)d_in[0];
  const float* Wq = (const float*)d_in[1];  const float* bq = (const float*)d_in[2];
  const float* Wk = (const float*)d_in[3];  const float* bk = (const float*)d_in[4];
  const float* Wv = (const float*)d_in[5];  const float* bv = (const float*)d_in[6];
  const float* Wo = (const float*)d_in[7];  const float* bo = (const float*)d_in[8];
  const float* g1 = (const float*)d_in[9];  const float* be1 = (const float*)d_in[10];
  const float* me1 = (const float*)d_in[11]; const float* va1 = (const float*)d_in[12];
  const float* W1 = (const float*)d_in[13]; const float* b1 = (const float*)d_in[14];
  const float* W2 = (const float*)d_in[15]; const float* b2 = (const float*)d_in[16];
  const float* g2 = (const float*)d_in[17]; const float* be2 = (const float*)d_in[18];
  const float* me2 = (const float*)d_in[19]; const float* va2 = (const float*)d_in[20];
  const int* idxs = (const int*)d_in[21];
  int U = in_sizes[21] / 512;
  float* out = (float*)d_out;

  char* ws = (char*)d_ws;
  float* QC = (float*)(ws);                    // 8 MB: Q, then Ctx
  float* Kb = (float*)(ws + (8u << 20));       // 8 MB: K, then h bf16
  float* Vb = (float*)(ws + (16u << 20));      // 8 MB: V, then f bf16
  float* YT = (float*)(ws + (24u << 20));      // 8 MB: xT, then Y
  float* Xh = (float*)(ws + (32u << 20));      // 8 MB: res2 fp32
  unsigned short* Fb = (unsigned short*)Vb;
  unsigned short* Hb = (unsigned short*)Kb;
  // Tier A (ws >= 176 MB): Wb 64 MB @48 (W1b then W2b), P 64 MB @112
  unsigned short* Wb = (unsigned short*)(ws + (48u << 20));
  float* PA = (float*)(ws + (112u << 20));
  // Tier B (ws >= 112 MB): round-5 layout
  float* P1 = (float*)(ws + (48u << 20));
  float* P2 = (float*)(ws + (80u << 20));
  bool tierA = ws_size >= (size_t)176 * (1u << 20);
  bool tierB = !tierA && ws_size >= (size_t)112 * (1u << 20);

  dim3 b256(256);
  transpose_k<<<dim3(4, 512), b256, 0, stream>>>(x, YT, 16384, 128);
  qkv_k<<<dim3(128, 2), b256, 0, stream>>>(YT, Wq, bq, Wk, bk, Wv, bv, QC, Kb, Vb);
  topattn_k<<<dim3(1024), dim3(512), 0, stream>>>(QC, Kb, Vb, idxs, QC, U);
  oproj_k<<<dim3(128, 2), b256, 0, stream>>>(QC, Wo, bo, YT);
  bn1t_k<<<dim3(512, 4), b256, 0, stream>>>(YT, x, g1, be1, me1, va1, Xh, Fb);

  if (tierA) {
    wcvt_k<<<dim3(2048), b256, 0, stream>>>(W1, Wb, (8192 * 4096) / 4);
    gemm_bf<<<dim3(1024), b256, 0, stream>>>(Fb, Wb, 4096, 8192, 4, 8, 4, PA, 512);
    red_k<0><<<dim3(4096), b256, 0, stream>>>(PA, 4, b1, nullptr, nullptr, nullptr,
                                              nullptr, nullptr, Hb, nullptr, 8192,
                                              512 * 8192);
    wcvt_k<<<dim3(2048), b256, 0, stream>>>(W2, Wb, (4096 * 8192) / 4);
    gemm_bf<<<dim3(1024), b256, 0, stream>>>(Hb, Wb, 8192, 4096, 4, 4, 8, PA, 512);
    red_k<1><<<dim3(2048), b256, 0, stream>>>(PA, 8, b2, Xh, g2, be2, me2, va2,
                                              nullptr, out, 4096, 512 * 4096);
  } else if (tierB) {
    gemm_ps<4, 2, 2><<<dim3(1024), b256, 0, stream>>>(
        Fb, W1, nullptr, 4096, 8192, 4, 16, 2, P1, 512,
        nullptr, nullptr, nullptr, nullptr, nullptr, nullptr, nullptr);
    red_k<0><<<dim3(4096), b256, 0, stream>>>(P1, 2, b1, nullptr, nullptr, nullptr,
                                              nullptr, nullptr, Hb, nullptr, 8192,
                                              512 * 8192);
    gemm_ps<4, 2, 2><<<dim3(1024), b256, 0, stream>>>(
        Hb, W2, nullptr, 8192, 4096, 4, 8, 4, P2, 512,
        nullptr, nullptr, nullptr, nullptr, nullptr, nullptr, nullptr);
    red_k<1><<<dim3(2048), b256, 0, stream>>>(P2, 4, b2, Xh, g2, be2, me2, va2,
                                              nullptr, out, 4096, 512 * 4096);
  } else {
    gemm_ps<4, 2, 0><<<dim3(512), b256, 0, stream>>>(
        Fb, W1, b1, 4096, 8192, 4, 16, 1, nullptr, 512,
        Hb, nullptr, nullptr, nullptr, nullptr, nullptr, nullptr);
    gemm_ps<4, 2, 1><<<dim3(256), b256, 0, stream>>>(
        Hb, W2, b2, 8192, 4096, 4, 8, 1, nullptr, 512,
        nullptr, Xh, g2, be2, me2, va2, out);
  }
}